// Round 15
// baseline (364.763 us; speedup 1.0000x reference)
//
#include <hip/hip_runtime.h>
#include <hip/hip_bf16.h>

#define BB 4
#define TT 2048
#define DD 256
#define HH 4
#define HDD 64
#define NROW 8192   // B*T
#define NQ 128      // MAX_BITS*2

typedef __hip_bfloat16 bf16;
typedef __attribute__((ext_vector_type(8))) short bf8v;   // 8 bf16 = 4 VGPR
typedef __attribute__((ext_vector_type(4))) short bf4v;   // 4 bf16 = 2 VGPR
typedef __attribute__((ext_vector_type(4))) float f4v;
typedef __attribute__((ext_vector_type(2))) unsigned int u2v;

__device__ __forceinline__ bf16 f2b(float v){ return __float2bfloat16(v); }
__device__ __forceinline__ short f2bs(float v){
    bf16 h = __float2bfloat16(v);
    return *reinterpret_cast<short*>(&h);
}
__device__ __forceinline__ float bs2f(short s){
    bf16 h = *reinterpret_cast<bf16*>(&s);
    return __bfloat162float(h);
}
__device__ __forceinline__ float rl(float v, int l){
    return __uint_as_float(__builtin_amdgcn_readlane(__float_as_uint(v), l));
}

// async global->LDS, 16B/lane; dest wave-uniform base, lane i at base+i*16
// (m104). __syncthreads() drains vmcnt (m97). R5 harness-verified.
__device__ __forceinline__ void gll16(const void* g, void* l){
    __builtin_amdgcn_global_load_lds((const __attribute__((address_space(1))) unsigned int*)g,
                                     (__attribute__((address_space(3))) unsigned int*)l, 16, 0, 0);
}

// DPP rotate ops within 16-lane row (all lanes valid, full masks)
#define DPP_ROR_ADD(v, ctrl) \
    ((v) + __int_as_float(__builtin_amdgcn_update_dpp(0, __float_as_int(v), (ctrl), 0xF, 0xF, false)))
#define DPP_ROR_MAX(v, ctrl) \
    fmaxf((v), __int_as_float(__builtin_amdgcn_update_dpp(0, __float_as_int(v), (ctrl), 0xF, 0xF, false)))

// gfx950 permlane swap via builtin (R4 fix: asm "+v"(a),"+v"(b) with a==b let
// regalloc coalesce both into ONE VGPR -> in-place garbage shuffle).
__device__ __forceinline__ void plswap16(float v, float& a, float& b){
#if __has_builtin(__builtin_amdgcn_permlane16_swap)
    u2v r = __builtin_amdgcn_permlane16_swap(__float_as_uint(v), __float_as_uint(v), false, false);
    a = __uint_as_float(r.x); b = __uint_as_float(r.y);
#else
    a = v; b = v;
    asm volatile("" : "+v"(b));
    asm("v_permlane16_swap_b32 %0, %1" : "+v"(a), "+v"(b));
#endif
}
__device__ __forceinline__ void plswap32(float v, float& a, float& b){
#if __has_builtin(__builtin_amdgcn_permlane32_swap)
    u2v r = __builtin_amdgcn_permlane32_swap(__float_as_uint(v), __float_as_uint(v), false, false);
    a = __uint_as_float(r.x); b = __uint_as_float(r.y);
#else
    a = v; b = v;
    asm volatile("" : "+v"(b));
    asm("v_permlane32_swap_b32 %0, %1" : "+v"(a), "+v"(b));
#endif
}
__device__ __forceinline__ float swap16_add(float v){ float a,b; plswap16(v,a,b); return a + b; }
__device__ __forceinline__ float swap32_add(float v){ float a,b; plswap32(v,a,b); return a + b; }
__device__ __forceinline__ float swap16_max(float v){ float a,b; plswap16(v,a,b); return fmaxf(a,b); }
__device__ __forceinline__ float swap32_max(float v){ float a,b; plswap32(v,a,b); return fmaxf(a,b); }
__device__ __forceinline__ float wsum(float v){
    v = DPP_ROR_ADD(v, 0x121); v = DPP_ROR_ADD(v, 0x122);
    v = DPP_ROR_ADD(v, 0x124); v = DPP_ROR_ADD(v, 0x128);
    v = swap16_add(v); v = swap32_add(v);
    return v;
}
__device__ __forceinline__ float wmax(float v){
    v = DPP_ROR_MAX(v, 0x121); v = DPP_ROR_MAX(v, 0x122);
    v = DPP_ROR_MAX(v, 0x124); v = DPP_ROR_MAX(v, 0x128);
    v = swap16_max(v); v = swap32_max(v);
    return v;
}

#define MFMA32(A,B,C) __builtin_amdgcn_mfma_f32_16x16x32_bf16((A),(B),(C),0,0,0)
#if __has_builtin(__builtin_amdgcn_mfma_f32_16x16x16bf16_1k)
#define MFMA16(A,B,C) __builtin_amdgcn_mfma_f32_16x16x16bf16_1k((A),(B),(C),0,0,0)
#else
__device__ __forceinline__ f4v mfma16_asm(bf4v a, bf4v b, f4v c){
    f4v d;
    asm("v_mfma_f32_16x16x16_bf16 %0, %1, %2, %3" : "=v"(d) : "v"(a), "v"(b), "v"(c));
    return d;
}
#define MFMA16(A,B,C) mfma16_asm((A),(B),(C))
#endif

// ---------------- fused embed + layer-0 LN1 ----------------
__global__ __launch_bounds__(256) void k_embln(const int* __restrict__ tok,
                                               const float* __restrict__ emb,
                                               const float* __restrict__ w,
                                               const float* __restrict__ b,
                                               float* __restrict__ x,
                                               bf16* __restrict__ Y){
    int row = blockIdx.x*4 + (threadIdx.x >> 6);
    int lane = threadIdx.x & 63;
    f4v v = *(const f4v*)(emb + (long)tok[row]*DD + lane*4);
    *(f4v*)(x + (long)row*DD + lane*4) = v;
    float s  = (v[0]+v[1]) + (v[2]+v[3]);
    float s2 = (v[0]*v[0]+v[1]*v[1]) + (v[2]*v[2]+v[3]*v[3]);
    s = wsum(s); s2 = wsum(s2);
    float mu  = s * (1.0f/DD);
    float var = s2 * (1.0f/DD) - mu*mu;
    float rs  = rsqrtf(var + 1e-5f);
    f4v wv4 = *(const f4v*)(w + lane*4);
    f4v bv4 = *(const f4v*)(b + lane*4);
    bf4v o;
    #pragma unroll
    for (int i=0;i<4;i++) o[i] = f2bs((v[i]-mu)*rs*wv4[i] + bv4[i]);
    *(bf4v*)(Y + (long)row*DD + lane*4) = o;
}

// ---------------- all 8 weight cast+transposes + misc prologue in ONE dispatch ----------------
__global__ __launch_bounds__(256) void k_wtall(const float* __restrict__ qkvw,
                                               const float* __restrict__ projw,
                                               const float* __restrict__ f1w,
                                               const float* __restrict__ f2w,
                                               bf16* __restrict__ wt,
                                               const float* __restrict__ oq, bf16* __restrict__ oqb,
                                               float* __restrict__ cosT, float* __restrict__ sinT,
                                               const float* __restrict__ w2, float* __restrict__ w2t){
    __shared__ float t[32][33];
    int z = blockIdx.z;
    if (z == 8){
        int bid = blockIdx.y*32 + blockIdx.x;
        if (bid >= 256) return;
        int gid = bid*256 + threadIdx.y*32 + threadIdx.x;   // 0..65535
        int tt = gid >> 5, dd = gid & 31;
        float invf = powf(10000.0f, -(float)(2*dd)/64.0f);
        float ang = (float)tt * invf;
        float sn, cs;
        sincosf(ang, &sn, &cs);
        cosT[gid] = cs; sinT[gid] = sn;
        if (gid < NQ*DD) oqb[gid] = f2b(oq[gid]);
        if (gid < 4096){ int j = gid >> 6, k = gid & 63; w2t[gid] = w2[k*64 + j]; }
        return;
    }
    int l = z >> 2, type = z & 3;
    long L = (long)l*786432;
    int K, M; const float* src; long doff;
    if (type == 0){ K=256;  M=768;  src = qkvw + (long)l*256*768;  doff = L; }
    else if (type == 1){ K=256;  M=256;  src = projw + (long)l*256*256; doff = L + 196608; }
    else if (type == 2){ K=256;  M=1024; src = f1w  + (long)l*256*1024; doff = L + 262144; }
    else               { K=1024; M=256;  src = f2w  + (long)l*1024*256; doff = L + 524288; }
    int m0 = blockIdx.x*32, k0 = blockIdx.y*32;
    if (m0 >= M || k0 >= K) return;
    bf16* dst = wt + doff;
    int tx = threadIdx.x, ty = threadIdx.y;     // 32 x 8
    #pragma unroll
    for (int i=0;i<4;i++)
        t[ty+i*8][tx] = src[(long)(k0+ty+i*8)*M + m0 + tx];
    __syncthreads();
    #pragma unroll
    for (int i=0;i<4;i++)
        dst[(long)(m0+ty+i*8)*K + k0 + tx] = f2b(t[tx][ty+i*8]);
}

// ---------------- layernorm, bf16 out (1 wave = 1 row, barrier-free) ----------------
__global__ __launch_bounds__(256) void k_lnb(const float* __restrict__ X,
                                             const float* __restrict__ w,
                                             const float* __restrict__ b,
                                             bf16* __restrict__ Y){
    int row = blockIdx.x*4 + (threadIdx.x >> 6);
    int lane = threadIdx.x & 63;
    f4v v = *(const f4v*)(X + (long)row*DD + lane*4);
    float s  = (v[0]+v[1]) + (v[2]+v[3]);
    float s2 = (v[0]*v[0]+v[1]*v[1]) + (v[2]*v[2]+v[3]*v[3]);
    s = wsum(s); s2 = wsum(s2);
    float mu  = s * (1.0f/DD);
    float var = s2 * (1.0f/DD) - mu*mu;
    float rs  = rsqrtf(var + 1e-5f);
    f4v wv4 = *(const f4v*)(w + lane*4);
    f4v bv4 = *(const f4v*)(b + lane*4);
    bf4v o;
    #pragma unroll
    for (int i=0;i<4;i++) o[i] = f2bs((v[i]-mu)*rs*wv4[i] + bv4[i]);
    *(bf4v*)(Y + (long)row*DD + lane*4) = o;
}

// ---------------- final layernorm: bf16 out + g[n] = y . ow ----------------
__global__ __launch_bounds__(256) void k_lnf(const float* __restrict__ X,
                                             const float* __restrict__ w,
                                             const float* __restrict__ b,
                                             const float* __restrict__ ow,
                                             bf16* __restrict__ Yb,
                                             float* __restrict__ g){
    int row = blockIdx.x*4 + (threadIdx.x >> 6);
    int lane = threadIdx.x & 63;
    f4v v = *(const f4v*)(X + (long)row*DD + lane*4);
    float s  = (v[0]+v[1]) + (v[2]+v[3]);
    float s2 = (v[0]*v[0]+v[1]*v[1]) + (v[2]*v[2]+v[3]*v[3]);
    s = wsum(s); s2 = wsum(s2);
    float mu  = s * (1.0f/DD);
    float var = s2 * (1.0f/DD) - mu*mu;
    float rs  = rsqrtf(var + 1e-5f);
    f4v wv4 = *(const f4v*)(w + lane*4);
    f4v bv4 = *(const f4v*)(b + lane*4);
    f4v ov4 = *(const f4v*)(ow + lane*4);
    bf4v o;
    float gp = 0.f;
    #pragma unroll
    for (int i=0;i<4;i++){
        float y = (v[i]-mu)*rs*wv4[i] + bv4[i];
        o[i] = f2bs(y);
        gp += y * ov4[i];
    }
    *(bf4v*)(Yb + (long)row*DD + lane*4) = o;
    gp = wsum(gp);
    if (lane == 0) g[row] = gp;
}

// ---------------- MFMA GEMM 128x64 tile (ffn1): R15 gll16 + pre-swizzled src ----------------
// Rule 21: linear LDS dest (gll16 writes base+lane*16) + INVERSE-swizzled
// global source (lane owning LDS chunk (row,c) loads global chunk c^(row&7))
// + swizzled read (unchanged). Removes VGPR round-trip + all ds_writes
// (m151: 874 vs 646 TF). One barrier/iter (T3 2-phase: loads in flight
// across compute, drained at next barrier).
__global__ __launch_bounds__(256) void k_mgemm(const bf16* __restrict__ A,
                                               const bf16* __restrict__ Wt,
                                               const float* __restrict__ bias,
                                               float* __restrict__ Cf,
                                               bf16* __restrict__ Cb,
                                               int K, int M, int mode){
    __shared__ short As[2][128*64];
    __shared__ short Ws[2][64*64];
    int tid = threadIdx.x;
    int lane = tid & 63, wv = tid >> 6;
    int n0 = blockIdx.y * 128, m0 = blockIdx.x * 64;
    int rbase = (wv >> 1) * 64, cbase = (wv & 1) * 32;
    f4v acc[4][2] = {};
    long asrc[4], wsrc[2];
    #pragma unroll
    for (int c=0;c<4;c++){
        int idx = c*256 + tid, row = idx>>3, ch = idx&7;
        asrc[c] = (long)(n0 + row)*K + ((ch ^ (row&7))<<3);
    }
    #pragma unroll
    for (int c=0;c<2;c++){
        int idx = c*256 + tid, row = idx>>3, ch = idx&7;
        wsrc[c] = (long)(m0 + row)*K + ((ch ^ (row&7))<<3);
    }
    // prologue: stage k0=0 into buf 0
    #pragma unroll
    for (int c=0;c<4;c++) gll16(A  + asrc[c], &As[0][(c*256 + wv*64)*8]);
    #pragma unroll
    for (int c=0;c<2;c++) gll16(Wt + wsrc[c], &Ws[0][(c*256 + wv*64)*8]);
    int buf = 0;
    for (int k0 = 0; k0 < K; k0 += 64){
        __syncthreads();    // drains vmcnt: buf ready; also WAR fence for buf^1
        if (k0 + 64 < K){   // next tile in flight across this iter's compute
            #pragma unroll
            for (int c=0;c<4;c++) gll16(A  + asrc[c] + k0 + 64, &As[buf^1][(c*256 + wv*64)*8]);
            #pragma unroll
            for (int c=0;c<2;c++) gll16(Wt + wsrc[c] + k0 + 64, &Ws[buf^1][(c*256 + wv*64)*8]);
        }
        int k8 = (lane >> 4) << 3;
        #pragma unroll
        for (int h=0; h<2; h++){
            bf8v af[4], bfr[2];
            #pragma unroll
            for (int i=0;i<4;i++){
                int row = rbase + i*16 + (lane&15);
                af[i] = *(bf8v*)&As[buf][row*64 + ((h*32 + k8) ^ ((row&7)<<3))];
            }
            #pragma unroll
            for (int j=0;j<2;j++){
                int row = cbase + j*16 + (lane&15);
                bfr[j] = *(bf8v*)&Ws[buf][row*64 + ((h*32 + k8) ^ ((row&7)<<3))];
            }
            #pragma unroll
            for (int i=0;i<4;i++)
                #pragma unroll
                for (int j=0;j<2;j++)
                    acc[i][j] = MFMA32(af[i], bfr[j], acc[i][j]);
        }
        buf ^= 1;
    }
    int rq = (lane >> 4) * 4;
    int cl = lane & 15;
    #pragma unroll
    for (int i=0;i<4;i++){
        #pragma unroll
        for (int j=0;j<2;j++){
            int m = m0 + cbase + j*16 + cl;
            float bs = bias[m];
            #pragma unroll
            for (int r=0;r<4;r++){
                int n = n0 + rbase + i*16 + rq + r;
                float v = acc[i][j][r] + bs;
                long idx = (long)n*M + m;
                if (mode == 0)      Cf[idx] = v;
                else if (mode == 1) Cf[idx] += v;
                else if (mode == 2) Cb[idx] = f2b(0.5f*v*(1.0f + erff(v*0.70710678118654752f)));
                else                Cb[idx] = f2b(v);
            }
        }
    }
}

// ---------------- MFMA GEMM 64x64 tile (proj/ffn2): R15 gll16 + pre-swizzled src ----------------
__global__ __launch_bounds__(256) void k_mgemm64(const bf16* __restrict__ A,
                                                 const bf16* __restrict__ Wt,
                                                 const float* __restrict__ bias,
                                                 float* __restrict__ Cf,
                                                 bf16* __restrict__ Cb,
                                                 int K, int M, int mode){
    __shared__ short As[2][64*64];
    __shared__ short Ws[2][64*64];
    int tid = threadIdx.x;
    int lane = tid & 63, wv = tid >> 6;
    int n0 = blockIdx.y * 64, m0 = blockIdx.x * 64;
    int rbase = (wv >> 1) * 32, cbase = (wv & 1) * 32;
    f4v acc[2][2] = {};
    long asrc[2], wsrc[2];
    #pragma unroll
    for (int c=0;c<2;c++){
        int idx = c*256 + tid, row = idx>>3, ch = idx&7;
        asrc[c] = (long)(n0 + row)*K + ((ch ^ (row&7))<<3);
        wsrc[c] = (long)(m0 + row)*K + ((ch ^ (row&7))<<3);
    }
    #pragma unroll
    for (int c=0;c<2;c++){
        gll16(A  + asrc[c], &As[0][(c*256 + wv*64)*8]);
        gll16(Wt + wsrc[c], &Ws[0][(c*256 + wv*64)*8]);
    }
    int buf = 0;
    for (int k0 = 0; k0 < K; k0 += 64){
        __syncthreads();
        if (k0 + 64 < K){
            #pragma unroll
            for (int c=0;c<2;c++){
                gll16(A  + asrc[c] + k0 + 64, &As[buf^1][(c*256 + wv*64)*8]);
                gll16(Wt + wsrc[c] + k0 + 64, &Ws[buf^1][(c*256 + wv*64)*8]);
            }
        }
        int k8 = (lane >> 4) << 3;
        #pragma unroll
        for (int h=0; h<2; h++){
            bf8v af[2], bfr[2];
            #pragma unroll
            for (int i=0;i<2;i++){
                int row = rbase + i*16 + (lane&15);
                af[i] = *(bf8v*)&As[buf][row*64 + ((h*32 + k8) ^ ((row&7)<<3))];
            }
            #pragma unroll
            for (int j=0;j<2;j++){
                int row = cbase + j*16 + (lane&15);
                bfr[j] = *(bf8v*)&Ws[buf][row*64 + ((h*32 + k8) ^ ((row&7)<<3))];
            }
            #pragma unroll
            for (int i=0;i<2;i++)
                #pragma unroll
                for (int j=0;j<2;j++)
                    acc[i][j] = MFMA32(af[i], bfr[j], acc[i][j]);
        }
        buf ^= 1;
    }
    int rq = (lane >> 4) * 4;
    int cl = lane & 15;
    #pragma unroll
    for (int i=0;i<2;i++){
        #pragma unroll
        for (int j=0;j<2;j++){
            int m = m0 + cbase + j*16 + cl;
            float bs = bias[m];
            #pragma unroll
            for (int r=0;r<4;r++){
                int n = n0 + rbase + i*16 + rq + r;
                float v = acc[i][j][r] + bs;
                long idx = (long)n*M + m;
                if (mode == 0)      Cf[idx] = v;
                else if (mode == 1) Cf[idx] += v;
                else if (mode == 2) Cb[idx] = f2b(0.5f*v*(1.0f + erff(v*0.70710678118654752f)));
                else                Cb[idx] = f2b(v);
            }
        }
    }
}

// ---------------- fused QKV GEMM + bias + RoPE + V tile-transpose (R10-verified, frozen) ----------------
__global__ __launch_bounds__(256) void k_mgemmQKV(const bf16* __restrict__ A,
                                                  const bf16* __restrict__ Wt,
                                                  const float* __restrict__ bias,
                                                  const float* __restrict__ cosT,
                                                  const float* __restrict__ sinT,
                                                  bf16* __restrict__ qb,
                                                  bf16* __restrict__ kb,
                                                  bf16* __restrict__ vt){
    __shared__ short As[128*64];
    __shared__ short Ws[64*64];
    __shared__ short E[128][68];
    const int K = 256, M = 768;
    int tid = threadIdx.x;
    int lane = tid & 63, wv = tid >> 6;
    int n0 = blockIdx.y * 128, m0 = blockIdx.x * 64;
    int rbase = (wv >> 1) * 64, cbase = (wv & 1) * 32;
    f4v acc[4][2] = {};
    for (int k0 = 0; k0 < K; k0 += 64){
        bf8v va[4], vw[2];
        #pragma unroll
        for (int c=0;c<4;c++){
            int idx = c*256 + tid;
            va[c] = *(const bf8v*)(A + (long)(n0 + (idx>>3))*K + k0 + ((idx&7)<<3));
        }
        #pragma unroll
        for (int c=0;c<2;c++){
            int idx = c*256 + tid;
            vw[c] = *(const bf8v*)(Wt + (long)(m0 + (idx>>3))*K + k0 + ((idx&7)<<3));
        }
        __syncthreads();
        #pragma unroll
        for (int c=0;c<4;c++){
            int idx = c*256 + tid, row = idx>>3;
            *(bf8v*)&As[row*64 + (((idx&7)<<3) ^ ((row&7)<<3))] = va[c];
        }
        #pragma unroll
        for (int c=0;c<2;c++){
            int idx = c*256 + tid, row = idx>>3;
            *(bf8v*)&Ws[row*64 + (((idx&7)<<3) ^ ((row&7)<<3))] = vw[c];
        }
        __syncthreads();
        int k8 = (lane >> 4) << 3;
        #pragma unroll
        for (int h=0; h<2; h++){
            bf8v af[4], bfr[2];
            #pragma unroll
            for (int i=0;i<4;i++){
                int row = rbase + i*16 + (lane&15);
                af[i] = *(bf8v*)&As[row*64 + ((h*32 + k8) ^ ((row&7)<<3))];
            }
            #pragma unroll
            for (int j=0;j<2;j++){
                int row = cbase + j*16 + (lane&15);
                bfr[j] = *(bf8v*)&Ws[row*64 + ((h*32 + k8) ^ ((row&7)<<3))];
            }
            #pragma unroll
            for (int i=0;i<4;i++)
                #pragma unroll
                for (int j=0;j<2;j++)
                    acc[i][j] = MFMA32(af[i], bfr[j], acc[i][j]);
        }
    }
    int rq = (lane >> 4) * 4;
    int cl = lane & 15;
    #pragma unroll
    for (int i=0;i<4;i++){
        #pragma unroll
        for (int j=0;j<2;j++){
            int cc = cbase + j*16 + cl;
            float bs = bias[m0 + cc];
            #pragma unroll
            for (int r=0;r<4;r++)
                E[rbase + i*16 + rq + r][cc] = f2bs(acc[i][j][r] + bs);
        }
    }
    __syncthreads();
    int part = m0 >> 8;
    int h = (m0 >> 6) & 3;
    int b = n0 >> 11;
    int t0 = n0 & 2047;
    int bh = b*HH + h;
    if (part < 2){
        bf16* dst0 = part ? kb : qb;
        int r2 = tid >> 2;
        int c0 = (tid & 3) * 16;
        int cpx = c0 ^ 32;
        #pragma unroll
        for (int half=0; half<2; half++){
            int row = half*64 + r2;
            int t = t0 + row;
            bf8v e0 = *(bf8v*)&E[row][c0];
            bf8v e1 = *(bf8v*)&E[row][c0+8];
            bf8v p0 = *(bf8v*)&E[row][cpx];
            bf8v p1 = *(bf8v*)&E[row][cpx+8];
            const float* ct = cosT + t*32;
            const float* st = sinT + t*32;
            short o[16];
            #pragma unroll
            for (int i=0;i<8;i++){
                int d = c0 + i, dd = d & 31;
                float cs = ct[dd], sn = st[dd];
                float v = bs2f(e0[i]), v2 = bs2f(p0[i]);
                o[i] = f2bs((d < 32) ? (v*cs - v2*sn) : (v*cs + v2*sn));
            }
            #pragma unroll
            for (int i=0;i<8;i++){
                int d = c0 + 8 + i, dd = d & 31;
                float cs = ct[dd], sn = st[dd];
                float v = bs2f(e1[i]), v2 = bs2f(p1[i]);
                o[8+i] = f2bs((d < 32) ? (v*cs - v2*sn) : (v*cs + v2*sn));
            }
            short* dp = (short*)dst0 + ((long)bh*TT + t)*64 + c0;
            *(bf8v*)dp     = *(bf8v*)&o[0];
            *(bf8v*)(dp+8) = *(bf8v*)&o[8];
        }
    } else {
        int tIdx0 = t0 >> 6;
        int d  = (tid & 127) >> 1;
        int k0 = (tid & 1) * 32;
        int tt = tid >> 7;
        short o[32];
        #pragma unroll
        for (int k=0;k<32;k++) o[k] = E[tt*64 + k0 + k][d];
        short* dp = (short*)vt + (((long)bh*32 + tIdx0 + tt)*64 + d)*64 + k0;
        *(bf8v*)dp      = *(bf8v*)&o[0];
        *(bf8v*)(dp+8)  = *(bf8v*)&o[8];
        *(bf8v*)(dp+16) = *(bf8v*)&o[16];
        *(bf8v*)(dp+24) = *(bf8v*)&o[24];
    }
}

// ---------------- MFMA flash causal attention (R4-exact, thrice-verified ~42us; PARKED) ----------------
__global__ __launch_bounds__(256) void k_fattn(const bf16* __restrict__ qb,
                                               const bf16* __restrict__ kb,
                                               const bf16* __restrict__ vt,
                                               bf16* __restrict__ ob){
    __shared__ short Ks[2][64][72];
    __shared__ short Vs[2][64][68];
    int bh = blockIdx.y;
    int qt = (int)(gridDim.x - 1) - (int)blockIdx.x;  // heavy tiles first
    int tid = threadIdx.x;
    int lane = tid & 63, w = tid >> 6;
    int col = lane & 15, quad = lane >> 4;
    int q0 = qt*64 + w*16;
    const bf16* qp = qb + ((long)bh*TT + q0 + col)*64 + quad*8;
    bf8v bq0 = *(const bf8v*)(qp);
    bf8v bq1 = *(const bf8v*)(qp + 32);
    f4v oc[4] = {};
    float lsum = 0.f;
    int qglob = q0 + col;
    int srow = tid >> 2, sc0 = (tid & 3) * 16;
    const short* kgb = (const short*)kb + ((long)bh*TT + srow)*64 + sc0;
    const short* vgb = (const short*)vt + (((long)bh*32)*64 + srow)*64 + sc0;

    bf8v pk0 = *(const bf8v*)kgb;
    bf8v pk1 = *(const bf8v*)(kgb + 8);
    bf8v pv0 = *(const bf8v*)vgb;
    bf8v pv1 = *(const bf8v*)(vgb + 8);
    *(bf8v*)&Ks[0][srow][sc0]     = pk0;
    *(bf8v*)&Ks[0][srow][sc0 + 8] = pk1;
    *(bf8v*)&Vs[0][srow][sc0]     = pv0;
    *(bf8v*)&Vs[0][srow][sc0 + 8] = pv1;

    int buf = 0;
    for (int kt=0; kt<=qt; kt++){
        __syncthreads();
        bool more = (kt < qt);
        if (more){
            const short* kg = kgb + (long)(kt+1)*4096;
            const short* vg = vgb + (long)(kt+1)*4096;
            pk0 = *(const bf8v*)kg;
            pk1 = *(const bf8v*)(kg + 8);
            pv0 = *(const bf8v*)vg;
            pv1 = *(const bf8v*)(vg + 8);
        }
        bool diag = (kt == qt);
        int ntmax = diag ? w : 3;
        bf4v bp[4];
        #pragma unroll
        for (int nt=0; nt<4; nt++){
            if (nt > ntmax) continue;
            bf8v ka0 = *(const bf8v*)&Ks[buf][nt*16 + col][quad*8];
            bf8v ka1 = *(const bf8v*)&Ks[buf][nt*16 + col][32 + quad*8];
            f4v st = {};
            st = MFMA32(ka0, bq0, st);
            st = MFMA32(ka1, bq1, st);
            int key0 = kt*64 + nt*16 + quad*4;
            bf4v pb;
            #pragma unroll
            for (int r=0; r<4; r++){
                float e = __expf(st[r]*0.125f);
                if (diag && (key0 + r > qglob)) e = 0.f;
                lsum += e;
                pb[r] = f2bs(e);
            }
            bp[nt] = pb;
        }
        #pragma unroll
        for (int dt=0; dt<4; dt++){
            #pragma unroll
            for (int nt=0; nt<4; nt++){
                if (nt > ntmax) continue;
                bf4v va = *(const bf4v*)&Vs[buf][dt*16 + col][nt*16 + quad*4];
                oc[dt] = MFMA16(va, bp[nt], oc[dt]);
            }
        }
        if (more){
            *(bf8v*)&Ks[buf^1][srow][sc0]     = pk0;
            *(bf8v*)&Ks[buf^1][srow][sc0 + 8] = pk1;
            *(bf8v*)&Vs[buf^1][srow][sc0]     = pv0;
            *(bf8v*)&Vs[buf^1][srow][sc0 + 8] = pv1;
        }
        buf ^= 1;
    }
    lsum += __shfl_xor(lsum, 16, 64);
    lsum += __shfl_xor(lsum, 32, 64);
    float linv = 1.0f / lsum;

    int b = bh / HH, h = bh % HH;
    long obase = ((long)b*TT + q0 + col)*DD + h*64 + quad*4;
    #pragma unroll
    for (int dt=0; dt<4; dt++){
        bf4v o4;
        #pragma unroll
        for (int r=0; r<4; r++) o4[r] = f2bs(oc[dt][r]*linv);
        *(bf4v*)(ob + obase + dt*16) = o4;
    }
}

// ---------------- pooling scores: S[b][q][t] = (oq[q] . xf[b,t]) / 16, MFMA ----------------
__global__ __launch_bounds__(256) void k_score(const bf16* __restrict__ oqb,
                                               const bf16* __restrict__ xfb,
                                               float* __restrict__ S){
    int b = blockIdx.y, t0 = blockIdx.x*32;
    int tid = threadIdx.x, lane = tid & 63, w = tid >> 6;
    int col = lane & 15, quad = lane >> 4, k8 = quad << 3;
    const bf16* xb = xfb + (long)b*TT*DD;
    f4v acc[2][2] = {};
    #pragma unroll
    for (int ko=0; ko<8; ko++){
        int kk = ko*32 + k8;
        bf8v a0 = *(const bf8v*)(oqb + (long)(w*32 +      col)*DD + kk);
        bf8v a1 = *(const bf8v*)(oqb + (long)(w*32 + 16 + col)*DD + kk);
        #pragma unroll
        for (int bt=0; bt<2; bt++){
            bf8v bv = *(const bf8v*)(xb + (long)(t0 + bt*16 + col)*DD + kk);
            acc[0][bt] = MFMA32(a0, bv, acc[0][bt]);
            acc[1][bt] = MFMA32(a1, bv, acc[1][bt]);
        }
    }
    #pragma unroll
    for (int qt2=0; qt2<2; qt2++){
        #pragma unroll
        for (int bt=0; bt<2; bt++){
            #pragma unroll
            for (int r=0; r<4; r++){
                int q = w*32 + qt2*16 + quad*4 + r;
                S[((long)b*NQ + q)*TT + t0 + bt*16 + col] = acc[qt2][bt][r]*0.0625f;
            }
        }
    }
}

// ---------------- softmax row + fused bit: one (b,q) per block ----------------
__global__ __launch_bounds__(256) void k_psoft(const float* __restrict__ S,
                                               const float* __restrict__ g,
                                               const float* __restrict__ obias,
                                               float* __restrict__ out_qattn,
                                               float* __restrict__ out_pairs,
                                               float* __restrict__ bits){
    __shared__ float cmax[4], cs[4], cg[4];
    int bq = blockIdx.x, b = bq >> 7;
    int tid = threadIdx.x, wv = tid >> 6, lane = tid & 63;
    const f4v* S4 = (const f4v*)(S + (long)bq*TT);
    f4v s0 = S4[tid], s1 = S4[tid + 256];
    float lmax = fmaxf(fmaxf(fmaxf(s0[0],s0[1]), fmaxf(s0[2],s0[3])),
                       fmaxf(fmaxf(s1[0],s1[1]), fmaxf(s1[2],s1[3])));
    lmax = wmax(lmax);
    if (lane == 0) cmax[wv] = lmax;
    __syncthreads();
    float m = fmaxf(fmaxf(cmax[0],cmax[1]), fmaxf(cmax[2],cmax[3]));
    const f4v* g4 = (const f4v*)(g + (long)b*TT);
    f4v gv0 = g4[tid], gv1 = g4[tid + 256];
    f4v e0, e1;
    #pragma unroll
    for (int i=0;i<4;i++){ e0[i] = __expf(s0[i]-m); e1[i] = __expf(s1[i]-m); }
    float lsum = (e0[0]+e0[1]+e0[2]+e0[3]) + (e1[0]+e1[1]+e1[2]+e1[3]);
    float gdot = (e0[0]*gv0[0]+e0[1]*gv0[1]+e0[2]*gv0[2]+e0[3]*gv0[3])
               + (e1[0]*gv1[0]+e1[1]*gv1[1]+e1[2]*gv1[2]+e1[3]*gv1[3]);
    lsum = wsum(lsum); gdot = wsum(gdot);
    if (lane == 0){ cs[wv] = lsum; cg[wv] = gdot; }
    __syncthreads();
    float Lr = (cs[0]+cs[1]) + (cs[2]+cs[3]);
    float G  = (cg[0]+cg[1]) + (cg[2]+cg[3]);
    float inv = 1.0f / Lr;
    f4v* out4 = (f4v*)(out_qattn + (long)bq*TT);
    out4[tid]       = e0 * inv;
    out4[tid + 256] = e1 * inv;
    if (tid == 0){
        float bit = 1.0f/(1.0f + expf(-(G*inv + obias[0])));
        bits[bq] = bit;
        out_pairs[bq] = bit;
    }
}

// ---------------- sequential 64-step carry MLP ----------------
__global__ __launch_bounds__(64) void k_scan(const float* __restrict__ bits,
                                             const float* __restrict__ w1, const float* __restrict__ b1,
                                             const float* __restrict__ w2t, const float* __restrict__ b2,
                                             const float* __restrict__ w3, const float* __restrict__ b3,
                                             float* __restrict__ out_sum){
    __shared__ __align__(16) float h1s[2][64];
    int b = blockIdx.x, lane = threadIdx.x;
    float w1c0 = w1[lane], w1c1 = w1[64 + lane], w1c2 = w1[128 + lane];
    float b1v = b1[lane], b2v = b2[lane];
    float w3c0 = w3[lane*2 + 0], w3c1 = w3[lane*2 + 1];
    float b30 = b3[0], b31 = b3[1];
    const f4v* wrow = (const f4v*)(w2t + (long)lane*64);
    f4v c0v = wrow[0],  c1v = wrow[1],  c2v = wrow[2],  c3v = wrow[3],
        c4v = wrow[4],  c5v = wrow[5],  c6v = wrow[6],  c7v = wrow[7],
        c8v = wrow[8],  c9v = wrow[9],  cav = wrow[10], cbv = wrow[11],
        ccv = wrow[12], cdv = wrow[13], cev = wrow[14], cfv = wrow[15];
    float z0v = bits[b*128 + lane*2 + 0];
    float z1v = bits[b*128 + lane*2 + 1];
    float carry = 0.f;
    float a1 = rl(z0v, 0)*w1c0 + rl(z1v, 0)*w1c1 + b1v;
    for (int step=0; step<64; step++){
        float h1 = fmaxf(carry*w1c2 + a1, 0.f);
        float* hb = h1s[step & 1];
        hb[lane] = h1;
        __syncthreads();
        if (step < 63){   // next step's carry-independent part, hidden under LDS
            a1 = rl(z0v, step+1)*w1c0 + rl(z1v, step+1)*w1c1 + b1v;
        }
        const f4v* hv = (const f4v*)hb;
        f4v va = hv[0]*c0v,  vb = hv[1]*c1v,  vc = hv[2]*c2v,   vd = hv[3]*c3v;
        va += hv[4]*c4v;   vb += hv[5]*c5v;   vc += hv[6]*c6v;   vd += hv[7]*c7v;
        va += hv[8]*c8v;   vb += hv[9]*c9v;   vc += hv[10]*cav;  vd += hv[11]*cbv;
        va += hv[12]*ccv;  vb += hv[13]*cdv;  vc += hv[14]*cev;  vd += hv[15]*cfv;
        f4v vs = (va + vb) + (vc + vd);
        float h2 = fmaxf(((vs[0] + vs[1]) + (vs[2] + vs[3])) + b2v, 0.f);
        float t0 = h2*w3c0, t1 = h2*w3c1;
        t0 = DPP_ROR_ADD(t0, 0x121); t1 = DPP_ROR_ADD(t1, 0x121);   // ror:1
        t0 = DPP_ROR_ADD(t0, 0x122); t1 = DPP_ROR_ADD(t1, 0x122);   // ror:2
        t0 = DPP_ROR_ADD(t0, 0x124); t1 = DPP_ROR_ADD(t1, 0x124);   // ror:4
        t0 = DPP_ROR_ADD(t0, 0x128); t1 = DPP_ROR_ADD(t1, 0x128);   // ror:8
        t0 = swap16_add(t0); t1 = swap16_add(t1);
        t0 = swap32_add(t0); t1 = swap32_add(t1);
        float o0 = 1.0f/(1.0f + __expf(-(t0 + b30)));
        carry    = 1.0f/(1.0f + __expf(-(t1 + b31)));
        if (lane == 0) out_sum[b*65 + step] = o0;
    }
    if (lane == 0) out_sum[b*65 + 64] = carry;
}

extern "C" void kernel_launch(void* const* d_in, const int* in_sizes, int n_in,
                              void* d_out, int out_size, void* d_ws, size_t ws_size,
                              hipStream_t stream){
    const int*   tok   = (const int*)d_in[0];
    const float* emb   = (const float*)d_in[1];
    const float* ln1w  = (const float*)d_in[2];
    const float* ln1b  = (const float*)d_in[3];
    const float* qkvw  = (const float*)d_in[4];
    const float* qkvb  = (const float*)d_in[5];
    const float* projw = (const float*)d_in[6];
    const float* projb = (const float*)d_in[7];
    const float* ln2w  = (const float*)d_in[8];
    const float* ln2b  = (const float*)d_in[9];
    const float* f1w   = (const float*)d_in[10];
    const float* f1b   = (const float*)d_in[11];
    const float* f2w   = (const float*)d_in[12];
    const float* f2bb  = (const float*)d_in[13];
    const float* lnfw  = (const float*)d_in[14];
    const float* lnfb  = (const float*)d_in[15];
    const float* oq    = (const float*)d_in[16];
    const float* ow    = (const float*)d_in[17];
    const float* obias = (const float*)d_in[18];
    const float* w1    = (const float*)d_in[19];
    const float* b1    = (const float*)d_in[20];
    const float* w2    = (const float*)d_in[21];
    const float* b2    = (const float*)d_in[22];
    const float* w3    = (const float*)d_in[23];
    const float* b3    = (const float*)d_in[24];
    float* out = (float*)d_out;

    const long MB = 1048576;
    char* W = (char*)d_ws;
    float* x     = (float*)(W);            // [0,8M) residual fp32
    bf16*  attnb = (bf16*)(W + 8*MB);      // [8M,12M)
    bf16*  hb    = (bf16*)(W + 16*MB);     // [16M,32M) FFN hidden bf16
    bf16*  qb    = (bf16*)(W + 32*MB);     // [32M,36M)
    bf16*  kb    = (bf16*)(W + 36*MB);     // [36M,40M)
    bf16*  vt    = (bf16*)(W + 44*MB);     // [44M,48M) V tile-blocked [bh][kt][d][k]
    bf16*  xnb   = (bf16*)(W + 48*MB);     // [48M,52M) LN out bf16
    bf16*  wt    = (bf16*)(W + 52*MB);     // [52M,55M) weights bf16 K-major
    float* bits  = (float*)(W + 55*MB);    // 2 KB
    bf16*  oqb   = (bf16*)(W + 56*MB);     // 64 KB
    float* cosT  = (float*)(W + 57*MB);    // 256 KB
    float* sinT  = cosT + 65536;           // 256 KB
    float* w2t   = (float*)(W + 58*MB);    // 16 KB
    bf16*  xfb   = (bf16*)(W + 32*MB);     // final LN bf16 (aliases dead qb)
    float* g     = (float*)(W + 36*MB);    // 32 KB (aliases dead kb)
    float* S     = (float*)(W + 40*MB);    // [40M,44M) scores fp32
    // wt per-layer offsets (bf16 elems), layer stride 786432:
    //   qkvT +0 | projT +196608 | f1T +262144 | f2T +524288

    k_wtall<<<dim3(32, 32, 9), dim3(32,8), 0, stream>>>(qkvw, projw, f1w, f2w, wt,
                                                        oq, oqb, cosT, sinT, w2, w2t);

    k_embln<<<NROW/4, 256, 0, stream>>>(tok, emb, ln1w, ln1b, x, xnb);
    for (int l=0; l<2; l++){
        long L = (long)l*786432;
        if (l) k_lnb<<<NROW/4, 256, 0, stream>>>(x, ln1w + l*DD, ln1b + l*DD, xnb);
        k_mgemmQKV<<<dim3(768/64, 64), 256, 0, stream>>>(
            xnb, wt + L, qkvb + l*768, cosT, sinT, qb, kb, vt);
        k_fattn<<<dim3(TT/64, BB*HH), 256, 0, stream>>>(qb, kb, vt, attnb);
        k_mgemm64<<<dim3(256/64, NROW/64), 256, 0, stream>>>(
            attnb, wt + L + 196608, projb + l*DD, x, (bf16*)0, 256, 256, 1);
        k_lnb<<<NROW/4, 256, 0, stream>>>(x, ln2w + l*DD, ln2b + l*DD, xnb);
        k_mgemm<<<dim3(1024/64, 64), 256, 0, stream>>>(
            xnb, wt + L + 262144, f1b + l*1024, (float*)0, hb, 256, 1024, 2);
        k_mgemm64<<<dim3(256/64, NROW/64), 256, 0, stream>>>(
            hb, wt + L + 524288, f2bb + l*DD, x, (bf16*)0, 1024, 256, 1);
    }
    k_lnf<<<NROW/4, 256, 0, stream>>>(x, lnfw, lnfb, ow, xfb, g);
    // outputs: sum_all [0,260) | pairs [260,772) | q_attn [772, 772+4*128*2048)
    k_score<<<dim3(TT/32, BB), 256, 0, stream>>>(oqb, xfb, S);
    k_psoft<<<BB*NQ, 256, 0, stream>>>(S, g, obias, out + 772, out + 260, bits);
    k_scan<<<4, 64, 0, stream>>>(bits, w1, b1, w2t, b2, w3, b3, out);
}

// Round 16
// 356.592 us; speedup vs baseline: 1.0229x; 1.0229x over previous
//
#include <hip/hip_runtime.h>
#include <hip/hip_bf16.h>

#define BB 4
#define TT 2048
#define DD 256
#define HH 4
#define HDD 64
#define NROW 8192   // B*T
#define NQ 128      // MAX_BITS*2

typedef __hip_bfloat16 bf16;
typedef __attribute__((ext_vector_type(8))) short bf8v;   // 8 bf16 = 4 VGPR
typedef __attribute__((ext_vector_type(4))) short bf4v;   // 4 bf16 = 2 VGPR
typedef __attribute__((ext_vector_type(4))) float f4v;
typedef __attribute__((ext_vector_type(2))) unsigned int u2v;

__device__ __forceinline__ bf16 f2b(float v){ return __float2bfloat16(v); }
__device__ __forceinline__ short f2bs(float v){
    bf16 h = __float2bfloat16(v);
    return *reinterpret_cast<short*>(&h);
}
__device__ __forceinline__ float bs2f(short s){
    bf16 h = *reinterpret_cast<bf16*>(&s);
    return __bfloat162float(h);
}
__device__ __forceinline__ float rl(float v, int l){
    return __uint_as_float(__builtin_amdgcn_readlane(__float_as_uint(v), l));
}

// DPP rotate ops within 16-lane row (all lanes valid, full masks)
#define DPP_ROR_ADD(v, ctrl) \
    ((v) + __int_as_float(__builtin_amdgcn_update_dpp(0, __float_as_int(v), (ctrl), 0xF, 0xF, false)))
#define DPP_ROR_MAX(v, ctrl) \
    fmaxf((v), __int_as_float(__builtin_amdgcn_update_dpp(0, __float_as_int(v), (ctrl), 0xF, 0xF, false)))

// gfx950 permlane swap via builtin (R4 fix: asm "+v"(a),"+v"(b) with a==b let
// regalloc coalesce both into ONE VGPR -> in-place garbage shuffle).
__device__ __forceinline__ void plswap16(float v, float& a, float& b){
#if __has_builtin(__builtin_amdgcn_permlane16_swap)
    u2v r = __builtin_amdgcn_permlane16_swap(__float_as_uint(v), __float_as_uint(v), false, false);
    a = __uint_as_float(r.x); b = __uint_as_float(r.y);
#else
    a = v; b = v;
    asm volatile("" : "+v"(b));
    asm("v_permlane16_swap_b32 %0, %1" : "+v"(a), "+v"(b));
#endif
}
__device__ __forceinline__ void plswap32(float v, float& a, float& b){
#if __has_builtin(__builtin_amdgcn_permlane32_swap)
    u2v r = __builtin_amdgcn_permlane32_swap(__float_as_uint(v), __float_as_uint(v), false, false);
    a = __uint_as_float(r.x); b = __uint_as_float(r.y);
#else
    a = v; b = v;
    asm volatile("" : "+v"(b));
    asm("v_permlane32_swap_b32 %0, %1" : "+v"(a), "+v"(b));
#endif
}
__device__ __forceinline__ float swap16_add(float v){ float a,b; plswap16(v,a,b); return a + b; }
__device__ __forceinline__ float swap32_add(float v){ float a,b; plswap32(v,a,b); return a + b; }
__device__ __forceinline__ float swap16_max(float v){ float a,b; plswap16(v,a,b); return fmaxf(a,b); }
__device__ __forceinline__ float swap32_max(float v){ float a,b; plswap32(v,a,b); return fmaxf(a,b); }
__device__ __forceinline__ float wsum(float v){
    v = DPP_ROR_ADD(v, 0x121); v = DPP_ROR_ADD(v, 0x122);
    v = DPP_ROR_ADD(v, 0x124); v = DPP_ROR_ADD(v, 0x128);
    v = swap16_add(v); v = swap32_add(v);
    return v;
}
__device__ __forceinline__ float wmax(float v){
    v = DPP_ROR_MAX(v, 0x121); v = DPP_ROR_MAX(v, 0x122);
    v = DPP_ROR_MAX(v, 0x124); v = DPP_ROR_MAX(v, 0x128);
    v = swap16_max(v); v = swap32_max(v);
    return v;
}

#define MFMA32(A,B,C) __builtin_amdgcn_mfma_f32_16x16x32_bf16((A),(B),(C),0,0,0)
#if __has_builtin(__builtin_amdgcn_mfma_f32_16x16x16bf16_1k)
#define MFMA16(A,B,C) __builtin_amdgcn_mfma_f32_16x16x16bf16_1k((A),(B),(C),0,0,0)
#else
__device__ __forceinline__ f4v mfma16_asm(bf4v a, bf4v b, f4v c){
    f4v d;
    asm("v_mfma_f32_16x16x16_bf16 %0, %1, %2, %3" : "=v"(d) : "v"(a), "v"(b), "v"(c));
    return d;
}
#define MFMA16(A,B,C) mfma16_asm((A),(B),(C))
#endif

// ---------------- fused embed + layer-0 LN1 ----------------
__global__ __launch_bounds__(256) void k_embln(const int* __restrict__ tok,
                                               const float* __restrict__ emb,
                                               const float* __restrict__ w,
                                               const float* __restrict__ b,
                                               float* __restrict__ x,
                                               bf16* __restrict__ Y){
    int row = blockIdx.x*4 + (threadIdx.x >> 6);
    int lane = threadIdx.x & 63;
    f4v v = *(const f4v*)(emb + (long)tok[row]*DD + lane*4);
    *(f4v*)(x + (long)row*DD + lane*4) = v;
    float s  = (v[0]+v[1]) + (v[2]+v[3]);
    float s2 = (v[0]*v[0]+v[1]*v[1]) + (v[2]*v[2]+v[3]*v[3]);
    s = wsum(s); s2 = wsum(s2);
    float mu  = s * (1.0f/DD);
    float var = s2 * (1.0f/DD) - mu*mu;
    float rs  = rsqrtf(var + 1e-5f);
    f4v wv4 = *(const f4v*)(w + lane*4);
    f4v bv4 = *(const f4v*)(b + lane*4);
    bf4v o;
    #pragma unroll
    for (int i=0;i<4;i++) o[i] = f2bs((v[i]-mu)*rs*wv4[i] + bv4[i]);
    *(bf4v*)(Y + (long)row*DD + lane*4) = o;
}

// ---------------- all 8 weight cast+transposes + misc prologue in ONE dispatch ----------------
__global__ __launch_bounds__(256) void k_wtall(const float* __restrict__ qkvw,
                                               const float* __restrict__ projw,
                                               const float* __restrict__ f1w,
                                               const float* __restrict__ f2w,
                                               bf16* __restrict__ wt,
                                               const float* __restrict__ oq, bf16* __restrict__ oqb,
                                               float* __restrict__ cosT, float* __restrict__ sinT,
                                               const float* __restrict__ w2, float* __restrict__ w2t){
    __shared__ float t[32][33];
    int z = blockIdx.z;
    if (z == 8){
        int bid = blockIdx.y*32 + blockIdx.x;
        if (bid >= 256) return;
        int gid = bid*256 + threadIdx.y*32 + threadIdx.x;   // 0..65535
        int tt = gid >> 5, dd = gid & 31;
        float invf = powf(10000.0f, -(float)(2*dd)/64.0f);
        float ang = (float)tt * invf;
        float sn, cs;
        sincosf(ang, &sn, &cs);
        cosT[gid] = cs; sinT[gid] = sn;
        if (gid < NQ*DD) oqb[gid] = f2b(oq[gid]);
        if (gid < 4096){ int j = gid >> 6, k = gid & 63; w2t[gid] = w2[k*64 + j]; }
        return;
    }
    int l = z >> 2, type = z & 3;
    long L = (long)l*786432;
    int K, M; const float* src; long doff;
    if (type == 0){ K=256;  M=768;  src = qkvw + (long)l*256*768;  doff = L; }
    else if (type == 1){ K=256;  M=256;  src = projw + (long)l*256*256; doff = L + 196608; }
    else if (type == 2){ K=256;  M=1024; src = f1w  + (long)l*256*1024; doff = L + 262144; }
    else               { K=1024; M=256;  src = f2w  + (long)l*1024*256; doff = L + 524288; }
    int m0 = blockIdx.x*32, k0 = blockIdx.y*32;
    if (m0 >= M || k0 >= K) return;
    bf16* dst = wt + doff;
    int tx = threadIdx.x, ty = threadIdx.y;     // 32 x 8
    #pragma unroll
    for (int i=0;i<4;i++)
        t[ty+i*8][tx] = src[(long)(k0+ty+i*8)*M + m0 + tx];
    __syncthreads();
    #pragma unroll
    for (int i=0;i<4;i++)
        dst[(long)(m0+ty+i*8)*K + k0 + tx] = f2b(t[tx][ty+i*8]);
}

// ---------------- layernorm, bf16 out (1 wave = 1 row, barrier-free) ----------------
__global__ __launch_bounds__(256) void k_lnb(const float* __restrict__ X,
                                             const float* __restrict__ w,
                                             const float* __restrict__ b,
                                             bf16* __restrict__ Y){
    int row = blockIdx.x*4 + (threadIdx.x >> 6);
    int lane = threadIdx.x & 63;
    f4v v = *(const f4v*)(X + (long)row*DD + lane*4);
    float s  = (v[0]+v[1]) + (v[2]+v[3]);
    float s2 = (v[0]*v[0]+v[1]*v[1]) + (v[2]*v[2]+v[3]*v[3]);
    s = wsum(s); s2 = wsum(s2);
    float mu  = s * (1.0f/DD);
    float var = s2 * (1.0f/DD) - mu*mu;
    float rs  = rsqrtf(var + 1e-5f);
    f4v wv4 = *(const f4v*)(w + lane*4);
    f4v bv4 = *(const f4v*)(b + lane*4);
    bf4v o;
    #pragma unroll
    for (int i=0;i<4;i++) o[i] = f2bs((v[i]-mu)*rs*wv4[i] + bv4[i]);
    *(bf4v*)(Y + (long)row*DD + lane*4) = o;
}

// ---------------- final layernorm: bf16 out + g[n] = y . ow ----------------
__global__ __launch_bounds__(256) void k_lnf(const float* __restrict__ X,
                                             const float* __restrict__ w,
                                             const float* __restrict__ b,
                                             const float* __restrict__ ow,
                                             bf16* __restrict__ Yb,
                                             float* __restrict__ g){
    int row = blockIdx.x*4 + (threadIdx.x >> 6);
    int lane = threadIdx.x & 63;
    f4v v = *(const f4v*)(X + (long)row*DD + lane*4);
    float s  = (v[0]+v[1]) + (v[2]+v[3]);
    float s2 = (v[0]*v[0]+v[1]*v[1]) + (v[2]*v[2]+v[3]*v[3]);
    s = wsum(s); s2 = wsum(s2);
    float mu  = s * (1.0f/DD);
    float var = s2 * (1.0f/DD) - mu*mu;
    float rs  = rsqrtf(var + 1e-5f);
    f4v wv4 = *(const f4v*)(w + lane*4);
    f4v bv4 = *(const f4v*)(b + lane*4);
    f4v ov4 = *(const f4v*)(ow + lane*4);
    bf4v o;
    float gp = 0.f;
    #pragma unroll
    for (int i=0;i<4;i++){
        float y = (v[i]-mu)*rs*wv4[i] + bv4[i];
        o[i] = f2bs(y);
        gp += y * ov4[i];
    }
    *(bf4v*)(Yb + (long)row*DD + lane*4) = o;
    gp = wsum(gp);
    if (lane == 0) g[row] = gp;
}

// ---------------- MFMA GEMM 128x64 tile (ffn1): R11 dbuf (verified best; gll16 variant R15 regressed) ----------------
__global__ __launch_bounds__(256) void k_mgemm(const bf16* __restrict__ A,
                                               const bf16* __restrict__ Wt,
                                               const float* __restrict__ bias,
                                               float* __restrict__ Cf,
                                               bf16* __restrict__ Cb,
                                               int K, int M, int mode){
    __shared__ short As[2][128*64];
    __shared__ short Ws[2][64*64];
    int tid = threadIdx.x;
    int lane = tid & 63, wv = tid >> 6;
    int n0 = blockIdx.y * 128, m0 = blockIdx.x * 64;
    int rbase = (wv >> 1) * 64, cbase = (wv & 1) * 32;
    f4v acc[4][2] = {};
    bf8v va[4], vw[2];
    #pragma unroll
    for (int c=0;c<4;c++){
        int idx = c*256 + tid;                 // row = idx>>3 (0..127)
        va[c] = *(const bf8v*)(A + (long)(n0 + (idx>>3))*K + ((idx&7)<<3));
    }
    #pragma unroll
    for (int c=0;c<2;c++){
        int idx = c*256 + tid;                 // row 0..63
        vw[c] = *(const bf8v*)(Wt + (long)(m0 + (idx>>3))*K + ((idx&7)<<3));
    }
    int buf = 0;
    for (int k0 = 0; k0 < K; k0 += 64){
        #pragma unroll
        for (int c=0;c<4;c++){
            int idx = c*256 + tid, row = idx>>3;
            *(bf8v*)&As[buf][row*64 + (((idx&7)<<3) ^ ((row&7)<<3))] = va[c];
        }
        #pragma unroll
        for (int c=0;c<2;c++){
            int idx = c*256 + tid, row = idx>>3;
            *(bf8v*)&Ws[buf][row*64 + (((idx&7)<<3) ^ ((row&7)<<3))] = vw[c];
        }
        __syncthreads();    // buf ready; also fences i+2's rewrite
        if (k0 + 64 < K){   // next-tile loads overlap compute
            #pragma unroll
            for (int c=0;c<4;c++){
                int idx = c*256 + tid;
                va[c] = *(const bf8v*)(A + (long)(n0 + (idx>>3))*K + k0 + 64 + ((idx&7)<<3));
            }
            #pragma unroll
            for (int c=0;c<2;c++){
                int idx = c*256 + tid;
                vw[c] = *(const bf8v*)(Wt + (long)(m0 + (idx>>3))*K + k0 + 64 + ((idx&7)<<3));
            }
        }
        int k8 = (lane >> 4) << 3;
        #pragma unroll
        for (int h=0; h<2; h++){
            bf8v af[4], bfr[2];
            #pragma unroll
            for (int i=0;i<4;i++){
                int row = rbase + i*16 + (lane&15);
                af[i] = *(bf8v*)&As[buf][row*64 + ((h*32 + k8) ^ ((row&7)<<3))];
            }
            #pragma unroll
            for (int j=0;j<2;j++){
                int row = cbase + j*16 + (lane&15);
                bfr[j] = *(bf8v*)&Ws[buf][row*64 + ((h*32 + k8) ^ ((row&7)<<3))];
            }
            #pragma unroll
            for (int i=0;i<4;i++)
                #pragma unroll
                for (int j=0;j<2;j++)
                    acc[i][j] = MFMA32(af[i], bfr[j], acc[i][j]);
        }
        buf ^= 1;
    }
    int rq = (lane >> 4) * 4;
    int cl = lane & 15;
    #pragma unroll
    for (int i=0;i<4;i++){
        #pragma unroll
        for (int j=0;j<2;j++){
            int m = m0 + cbase + j*16 + cl;
            float bs = bias[m];
            #pragma unroll
            for (int r=0;r<4;r++){
                int n = n0 + rbase + i*16 + rq + r;
                float v = acc[i][j][r] + bs;
                long idx = (long)n*M + m;
                if (mode == 0)      Cf[idx] = v;
                else if (mode == 1) Cf[idx] += v;
                else if (mode == 2) Cb[idx] = f2b(0.5f*v*(1.0f + erff(v*0.70710678118654752f)));
                else                Cb[idx] = f2b(v);
            }
        }
    }
}

// ---------------- MFMA GEMM 64x64 tile (proj/ffn2: M=256, 2 blocks/CU) ----------------
__global__ __launch_bounds__(256) void k_mgemm64(const bf16* __restrict__ A,
                                                 const bf16* __restrict__ Wt,
                                                 const float* __restrict__ bias,
                                                 float* __restrict__ Cf,
                                                 bf16* __restrict__ Cb,
                                                 int K, int M, int mode){
    __shared__ short As[2][64*64];
    __shared__ short Ws[2][64*64];
    int tid = threadIdx.x;
    int lane = tid & 63, wv = tid >> 6;
    int n0 = blockIdx.y * 64, m0 = blockIdx.x * 64;
    int rbase = (wv >> 1) * 32, cbase = (wv & 1) * 32;
    f4v acc[2][2] = {};
    bf8v va[2], vw[2];
    #pragma unroll
    for (int c=0;c<2;c++){
        int idx = c*256 + tid;                 // row = idx>>3 (0..63)
        va[c] = *(const bf8v*)(A  + (long)(n0 + (idx>>3))*K + ((idx&7)<<3));
        vw[c] = *(const bf8v*)(Wt + (long)(m0 + (idx>>3))*K + ((idx&7)<<3));
    }
    int buf = 0;
    for (int k0 = 0; k0 < K; k0 += 64){
        #pragma unroll
        for (int c=0;c<2;c++){
            int idx = c*256 + tid, row = idx>>3;
            *(bf8v*)&As[buf][row*64 + (((idx&7)<<3) ^ ((row&7)<<3))] = va[c];
            *(bf8v*)&Ws[buf][row*64 + (((idx&7)<<3) ^ ((row&7)<<3))] = vw[c];
        }
        __syncthreads();
        if (k0 + 64 < K){
            #pragma unroll
            for (int c=0;c<2;c++){
                int idx = c*256 + tid;
                va[c] = *(const bf8v*)(A  + (long)(n0 + (idx>>3))*K + k0 + 64 + ((idx&7)<<3));
                vw[c] = *(const bf8v*)(Wt + (long)(m0 + (idx>>3))*K + k0 + 64 + ((idx&7)<<3));
            }
        }
        int k8 = (lane >> 4) << 3;
        #pragma unroll
        for (int h=0; h<2; h++){
            bf8v af[2], bfr[2];
            #pragma unroll
            for (int i=0;i<2;i++){
                int row = rbase + i*16 + (lane&15);
                af[i] = *(bf8v*)&As[buf][row*64 + ((h*32 + k8) ^ ((row&7)<<3))];
            }
            #pragma unroll
            for (int j=0;j<2;j++){
                int row = cbase + j*16 + (lane&15);
                bfr[j] = *(bf8v*)&Ws[buf][row*64 + ((h*32 + k8) ^ ((row&7)<<3))];
            }
            #pragma unroll
            for (int i=0;i<2;i++)
                #pragma unroll
                for (int j=0;j<2;j++)
                    acc[i][j] = MFMA32(af[i], bfr[j], acc[i][j]);
        }
        buf ^= 1;
    }
    int rq = (lane >> 4) * 4;
    int cl = lane & 15;
    #pragma unroll
    for (int i=0;i<2;i++){
        #pragma unroll
        for (int j=0;j<2;j++){
            int m = m0 + cbase + j*16 + cl;
            float bs = bias[m];
            #pragma unroll
            for (int r=0;r<4;r++){
                int n = n0 + rbase + i*16 + rq + r;
                float v = acc[i][j][r] + bs;
                long idx = (long)n*M + m;
                if (mode == 0)      Cf[idx] = v;
                else if (mode == 1) Cf[idx] += v;
                else if (mode == 2) Cb[idx] = f2b(0.5f*v*(1.0f + erff(v*0.70710678118654752f)));
                else                Cb[idx] = f2b(v);
            }
        }
    }
}

// ---------------- fused QKV GEMM + bias + RoPE + V tile-transpose (R10-verified) ----------------
__global__ __launch_bounds__(256) void k_mgemmQKV(const bf16* __restrict__ A,
                                                  const bf16* __restrict__ Wt,
                                                  const float* __restrict__ bias,
                                                  const float* __restrict__ cosT,
                                                  const float* __restrict__ sinT,
                                                  bf16* __restrict__ qb,
                                                  bf16* __restrict__ kb,
                                                  bf16* __restrict__ vt){
    __shared__ short As[128*64];
    __shared__ short Ws[64*64];
    __shared__ short E[128][68];
    const int K = 256, M = 768;
    int tid = threadIdx.x;
    int lane = tid & 63, wv = tid >> 6;
    int n0 = blockIdx.y * 128, m0 = blockIdx.x * 64;
    int rbase = (wv >> 1) * 64, cbase = (wv & 1) * 32;
    f4v acc[4][2] = {};
    for (int k0 = 0; k0 < K; k0 += 64){
        bf8v va[4], vw[2];
        #pragma unroll
        for (int c=0;c<4;c++){
            int idx = c*256 + tid;
            va[c] = *(const bf8v*)(A + (long)(n0 + (idx>>3))*K + k0 + ((idx&7)<<3));
        }
        #pragma unroll
        for (int c=0;c<2;c++){
            int idx = c*256 + tid;
            vw[c] = *(const bf8v*)(Wt + (long)(m0 + (idx>>3))*K + k0 + ((idx&7)<<3));
        }
        __syncthreads();
        #pragma unroll
        for (int c=0;c<4;c++){
            int idx = c*256 + tid, row = idx>>3;
            *(bf8v*)&As[row*64 + (((idx&7)<<3) ^ ((row&7)<<3))] = va[c];
        }
        #pragma unroll
        for (int c=0;c<2;c++){
            int idx = c*256 + tid, row = idx>>3;
            *(bf8v*)&Ws[row*64 + (((idx&7)<<3) ^ ((row&7)<<3))] = vw[c];
        }
        __syncthreads();
        int k8 = (lane >> 4) << 3;
        #pragma unroll
        for (int h=0; h<2; h++){
            bf8v af[4], bfr[2];
            #pragma unroll
            for (int i=0;i<4;i++){
                int row = rbase + i*16 + (lane&15);
                af[i] = *(bf8v*)&As[row*64 + ((h*32 + k8) ^ ((row&7)<<3))];
            }
            #pragma unroll
            for (int j=0;j<2;j++){
                int row = cbase + j*16 + (lane&15);
                bfr[j] = *(bf8v*)&Ws[row*64 + ((h*32 + k8) ^ ((row&7)<<3))];
            }
            #pragma unroll
            for (int i=0;i<4;i++)
                #pragma unroll
                for (int j=0;j<2;j++)
                    acc[i][j] = MFMA32(af[i], bfr[j], acc[i][j]);
        }
    }
    int rq = (lane >> 4) * 4;
    int cl = lane & 15;
    #pragma unroll
    for (int i=0;i<4;i++){
        #pragma unroll
        for (int j=0;j<2;j++){
            int cc = cbase + j*16 + cl;
            float bs = bias[m0 + cc];
            #pragma unroll
            for (int r=0;r<4;r++)
                E[rbase + i*16 + rq + r][cc] = f2bs(acc[i][j][r] + bs);
        }
    }
    __syncthreads();
    int part = m0 >> 8;
    int h = (m0 >> 6) & 3;
    int b = n0 >> 11;
    int t0 = n0 & 2047;
    int bh = b*HH + h;
    if (part < 2){
        bf16* dst0 = part ? kb : qb;
        int r2 = tid >> 2;
        int c0 = (tid & 3) * 16;
        int cpx = c0 ^ 32;
        #pragma unroll
        for (int half=0; half<2; half++){
            int row = half*64 + r2;
            int t = t0 + row;
            bf8v e0 = *(bf8v*)&E[row][c0];
            bf8v e1 = *(bf8v*)&E[row][c0+8];
            bf8v p0 = *(bf8v*)&E[row][cpx];
            bf8v p1 = *(bf8v*)&E[row][cpx+8];
            const float* ct = cosT + t*32;
            const float* st = sinT + t*32;
            short o[16];
            #pragma unroll
            for (int i=0;i<8;i++){
                int d = c0 + i, dd = d & 31;
                float cs = ct[dd], sn = st[dd];
                float v = bs2f(e0[i]), v2 = bs2f(p0[i]);
                o[i] = f2bs((d < 32) ? (v*cs - v2*sn) : (v*cs + v2*sn));
            }
            #pragma unroll
            for (int i=0;i<8;i++){
                int d = c0 + 8 + i, dd = d & 31;
                float cs = ct[dd], sn = st[dd];
                float v = bs2f(e1[i]), v2 = bs2f(p1[i]);
                o[8+i] = f2bs((d < 32) ? (v*cs - v2*sn) : (v*cs + v2*sn));
            }
            short* dp = (short*)dst0 + ((long)bh*TT + t)*64 + c0;
            *(bf8v*)dp     = *(bf8v*)&o[0];
            *(bf8v*)(dp+8) = *(bf8v*)&o[8];
        }
    } else {
        int tIdx0 = t0 >> 6;
        int d  = (tid & 127) >> 1;
        int k0 = (tid & 1) * 32;
        int tt = tid >> 7;
        short o[32];
        #pragma unroll
        for (int k=0;k<32;k++) o[k] = E[tt*64 + k0 + k][d];
        short* dp = (short*)vt + (((long)bh*32 + tIdx0 + tt)*64 + d)*64 + k0;
        *(bf8v*)dp      = *(bf8v*)&o[0];
        *(bf8v*)(dp+8)  = *(bf8v*)&o[8];
        *(bf8v*)(dp+16) = *(bf8v*)&o[16];
        *(bf8v*)(dp+24) = *(bf8v*)&o[24];
    }
}

// ---------------- MFMA flash causal attention (R4-exact, thrice-verified ~42us; PARKED) ----------------
__global__ __launch_bounds__(256) void k_fattn(const bf16* __restrict__ qb,
                                               const bf16* __restrict__ kb,
                                               const bf16* __restrict__ vt,
                                               bf16* __restrict__ ob){
    __shared__ short Ks[2][64][72];
    __shared__ short Vs[2][64][68];
    int bh = blockIdx.y;
    int qt = (int)(gridDim.x - 1) - (int)blockIdx.x;  // heavy tiles first
    int tid = threadIdx.x;
    int lane = tid & 63, w = tid >> 6;
    int col = lane & 15, quad = lane >> 4;
    int q0 = qt*64 + w*16;
    const bf16* qp = qb + ((long)bh*TT + q0 + col)*64 + quad*8;
    bf8v bq0 = *(const bf8v*)(qp);
    bf8v bq1 = *(const bf8v*)(qp + 32);
    f4v oc[4] = {};
    float lsum = 0.f;
    int qglob = q0 + col;
    int srow = tid >> 2, sc0 = (tid & 3) * 16;
    const short* kgb = (const short*)kb + ((long)bh*TT + srow)*64 + sc0;
    const short* vgb = (const short*)vt + (((long)bh*32)*64 + srow)*64 + sc0;

    bf8v pk0 = *(const bf8v*)kgb;
    bf8v pk1 = *(const bf8v*)(kgb + 8);
    bf8v pv0 = *(const bf8v*)vgb;
    bf8v pv1 = *(const bf8v*)(vgb + 8);
    *(bf8v*)&Ks[0][srow][sc0]     = pk0;
    *(bf8v*)&Ks[0][srow][sc0 + 8] = pk1;
    *(bf8v*)&Vs[0][srow][sc0]     = pv0;
    *(bf8v*)&Vs[0][srow][sc0 + 8] = pv1;

    int buf = 0;
    for (int kt=0; kt<=qt; kt++){
        __syncthreads();
        bool more = (kt < qt);
        if (more){
            const short* kg = kgb + (long)(kt+1)*4096;
            const short* vg = vgb + (long)(kt+1)*4096;
            pk0 = *(const bf8v*)kg;
            pk1 = *(const bf8v*)(kg + 8);
            pv0 = *(const bf8v*)vg;
            pv1 = *(const bf8v*)(vg + 8);
        }
        bool diag = (kt == qt);
        int ntmax = diag ? w : 3;
        bf4v bp[4];
        #pragma unroll
        for (int nt=0; nt<4; nt++){
            if (nt > ntmax) continue;
            bf8v ka0 = *(const bf8v*)&Ks[buf][nt*16 + col][quad*8];
            bf8v ka1 = *(const bf8v*)&Ks[buf][nt*16 + col][32 + quad*8];
            f4v st = {};
            st = MFMA32(ka0, bq0, st);
            st = MFMA32(ka1, bq1, st);
            int key0 = kt*64 + nt*16 + quad*4;
            bf4v pb;
            #pragma unroll
            for (int r=0; r<4; r++){
                float e = __expf(st[r]*0.125f);
                if (diag && (key0 + r > qglob)) e = 0.f;
                lsum += e;
                pb[r] = f2bs(e);
            }
            bp[nt] = pb;
        }
        #pragma unroll
        for (int dt=0; dt<4; dt++){
            #pragma unroll
            for (int nt=0; nt<4; nt++){
                if (nt > ntmax) continue;
                bf4v va = *(const bf4v*)&Vs[buf][dt*16 + col][nt*16 + quad*4];
                oc[dt] = MFMA16(va, bp[nt], oc[dt]);
            }
        }
        if (more){
            *(bf8v*)&Ks[buf^1][srow][sc0]     = pk0;
            *(bf8v*)&Ks[buf^1][srow][sc0 + 8] = pk1;
            *(bf8v*)&Vs[buf^1][srow][sc0]     = pv0;
            *(bf8v*)&Vs[buf^1][srow][sc0 + 8] = pv1;
        }
        buf ^= 1;
    }
    lsum += __shfl_xor(lsum, 16, 64);
    lsum += __shfl_xor(lsum, 32, 64);
    float linv = 1.0f / lsum;

    int b = bh / HH, h = bh % HH;
    long obase = ((long)b*TT + q0 + col)*DD + h*64 + quad*4;
    #pragma unroll
    for (int dt=0; dt<4; dt++){
        bf4v o4;
        #pragma unroll
        for (int r=0; r<4; r++) o4[r] = f2bs(oc[dt][r]*linv);
        *(bf4v*)(ob + obase + dt*16) = o4;
    }
}

// ---------------- pooling scores: S[b][q][t] = (oq[q] . xf[b,t]) / 16, MFMA ----------------
__global__ __launch_bounds__(256) void k_score(const bf16* __restrict__ oqb,
                                               const bf16* __restrict__ xfb,
                                               float* __restrict__ S){
    int b = blockIdx.y, t0 = blockIdx.x*32;
    int tid = threadIdx.x, lane = tid & 63, w = tid >> 6;
    int col = lane & 15, quad = lane >> 4, k8 = quad << 3;
    const bf16* xb = xfb + (long)b*TT*DD;
    f4v acc[2][2] = {};
    #pragma unroll
    for (int ko=0; ko<8; ko++){
        int kk = ko*32 + k8;
        bf8v a0 = *(const bf8v*)(oqb + (long)(w*32 +      col)*DD + kk);
        bf8v a1 = *(const bf8v*)(oqb + (long)(w*32 + 16 + col)*DD + kk);
        #pragma unroll
        for (int bt=0; bt<2; bt++){
            bf8v bv = *(const bf8v*)(xb + (long)(t0 + bt*16 + col)*DD + kk);
            acc[0][bt] = MFMA32(a0, bv, acc[0][bt]);
            acc[1][bt] = MFMA32(a1, bv, acc[1][bt]);
        }
    }
    #pragma unroll
    for (int qt2=0; qt2<2; qt2++){
        #pragma unroll
        for (int bt=0; bt<2; bt++){
            #pragma unroll
            for (int r=0; r<4; r++){
                int q = w*32 + qt2*16 + quad*4 + r;
                S[((long)b*NQ + q)*TT + t0 + bt*16 + col] = acc[qt2][bt][r]*0.0625f;
            }
        }
    }
}

// ---------------- softmax row + fused bit: one (b,q) per block ----------------
__global__ __launch_bounds__(256) void k_psoft(const float* __restrict__ S,
                                               const float* __restrict__ g,
                                               const float* __restrict__ obias,
                                               float* __restrict__ out_qattn,
                                               float* __restrict__ out_pairs,
                                               float* __restrict__ bits){
    __shared__ float cmax[4], cs[4], cg[4];
    int bq = blockIdx.x, b = bq >> 7;
    int tid = threadIdx.x, wv = tid >> 6, lane = tid & 63;
    const f4v* S4 = (const f4v*)(S + (long)bq*TT);
    f4v s0 = S4[tid], s1 = S4[tid + 256];
    float lmax = fmaxf(fmaxf(fmaxf(s0[0],s0[1]), fmaxf(s0[2],s0[3])),
                       fmaxf(fmaxf(s1[0],s1[1]), fmaxf(s1[2],s1[3])));
    lmax = wmax(lmax);
    if (lane == 0) cmax[wv] = lmax;
    __syncthreads();
    float m = fmaxf(fmaxf(cmax[0],cmax[1]), fmaxf(cmax[2],cmax[3]));
    const f4v* g4 = (const f4v*)(g + (long)b*TT);
    f4v gv0 = g4[tid], gv1 = g4[tid + 256];
    f4v e0, e1;
    #pragma unroll
    for (int i=0;i<4;i++){ e0[i] = __expf(s0[i]-m); e1[i] = __expf(s1[i]-m); }
    float lsum = (e0[0]+e0[1]+e0[2]+e0[3]) + (e1[0]+e1[1]+e1[2]+e1[3]);
    float gdot = (e0[0]*gv0[0]+e0[1]*gv0[1]+e0[2]*gv0[2]+e0[3]*gv0[3])
               + (e1[0]*gv1[0]+e1[1]*gv1[1]+e1[2]*gv1[2]+e1[3]*gv1[3]);
    lsum = wsum(lsum); gdot = wsum(gdot);
    if (lane == 0){ cs[wv] = lsum; cg[wv] = gdot; }
    __syncthreads();
    float Lr = (cs[0]+cs[1]) + (cs[2]+cs[3]);
    float G  = (cg[0]+cg[1]) + (cg[2]+cg[3]);
    float inv = 1.0f / Lr;
    f4v* out4 = (f4v*)(out_qattn + (long)bq*TT);
    out4[tid]       = e0 * inv;
    out4[tid + 256] = e1 * inv;
    if (tid == 0){
        float bit = 1.0f/(1.0f + expf(-(G*inv + obias[0])));
        bits[bq] = bit;
        out_pairs[bq] = bit;
    }
}

// ---------------- sequential 64-step carry MLP ----------------
__global__ __launch_bounds__(64) void k_scan(const float* __restrict__ bits,
                                             const float* __restrict__ w1, const float* __restrict__ b1,
                                             const float* __restrict__ w2t, const float* __restrict__ b2,
                                             const float* __restrict__ w3, const float* __restrict__ b3,
                                             float* __restrict__ out_sum){
    __shared__ __align__(16) float h1s[2][64];
    int b = blockIdx.x, lane = threadIdx.x;
    float w1c0 = w1[lane], w1c1 = w1[64 + lane], w1c2 = w1[128 + lane];
    float b1v = b1[lane], b2v = b2[lane];
    float w3c0 = w3[lane*2 + 0], w3c1 = w3[lane*2 + 1];
    float b30 = b3[0], b31 = b3[1];
    const f4v* wrow = (const f4v*)(w2t + (long)lane*64);
    f4v c0v = wrow[0],  c1v = wrow[1],  c2v = wrow[2],  c3v = wrow[3],
        c4v = wrow[4],  c5v = wrow[5],  c6v = wrow[6],  c7v = wrow[7],
        c8v = wrow[8],  c9v = wrow[9],  cav = wrow[10], cbv = wrow[11],
        ccv = wrow[12], cdv = wrow[13], cev = wrow[14], cfv = wrow[15];
    float z0v = bits[b*128 + lane*2 + 0];
    float z1v = bits[b*128 + lane*2 + 1];
    float carry = 0.f;
    float a1 = rl(z0v, 0)*w1c0 + rl(z1v, 0)*w1c1 + b1v;
    for (int step=0; step<64; step++){
        float h1 = fmaxf(carry*w1c2 + a1, 0.f);
        float* hb = h1s[step & 1];
        hb[lane] = h1;
        __syncthreads();
        if (step < 63){   // next step's carry-independent part, hidden under LDS
            a1 = rl(z0v, step+1)*w1c0 + rl(z1v, step+1)*w1c1 + b1v;
        }
        const f4v* hv = (const f4v*)hb;
        f4v va = hv[0]*c0v,  vb = hv[1]*c1v,  vc = hv[2]*c2v,   vd = hv[3]*c3v;
        va += hv[4]*c4v;   vb += hv[5]*c5v;   vc += hv[6]*c6v;   vd += hv[7]*c7v;
        va += hv[8]*c8v;   vb += hv[9]*c9v;   vc += hv[10]*cav;  vd += hv[11]*cbv;
        va += hv[12]*ccv;  vb += hv[13]*cdv;  vc += hv[14]*cev;  vd += hv[15]*cfv;
        f4v vs = (va + vb) + (vc + vd);
        float h2 = fmaxf(((vs[0] + vs[1]) + (vs[2] + vs[3])) + b2v, 0.f);
        float t0 = h2*w3c0, t1 = h2*w3c1;
        t0 = DPP_ROR_ADD(t0, 0x121); t1 = DPP_ROR_ADD(t1, 0x121);   // ror:1
        t0 = DPP_ROR_ADD(t0, 0x122); t1 = DPP_ROR_ADD(t1, 0x122);   // ror:2
        t0 = DPP_ROR_ADD(t0, 0x124); t1 = DPP_ROR_ADD(t1, 0x124);   // ror:4
        t0 = DPP_ROR_ADD(t0, 0x128); t1 = DPP_ROR_ADD(t1, 0x128);   // ror:8
        t0 = swap16_add(t0); t1 = swap16_add(t1);
        t0 = swap32_add(t0); t1 = swap32_add(t1);
        float o0 = 1.0f/(1.0f + __expf(-(t0 + b30)));
        carry    = 1.0f/(1.0f + __expf(-(t1 + b31)));
        if (lane == 0) out_sum[b*65 + step] = o0;
    }
    if (lane == 0) out_sum[b*65 + 64] = carry;
}

extern "C" void kernel_launch(void* const* d_in, const int* in_sizes, int n_in,
                              void* d_out, int out_size, void* d_ws, size_t ws_size,
                              hipStream_t stream){
    const int*   tok   = (const int*)d_in[0];
    const float* emb   = (const float*)d_in[1];
    const float* ln1w  = (const float*)d_in[2];
    const float* ln1b  = (const float*)d_in[3];
    const float* qkvw  = (const float*)d_in[4];
    const float* qkvb  = (const float*)d_in[5];
    const float* projw = (const float*)d_in[6];
    const float* projb = (const float*)d_in[7];
    const float* ln2w  = (const float*)d_in[8];
    const float* ln2b  = (const float*)d_in[9];
    const float* f1w   = (const float*)d_in[10];
    const float* f1b   = (const float*)d_in[11];
    const float* f2w   = (const float*)d_in[12];
    const float* f2bb  = (const float*)d_in[13];
    const float* lnfw  = (const float*)d_in[14];
    const float* lnfb  = (const float*)d_in[15];
    const float* oq    = (const float*)d_in[16];
    const float* ow    = (const float*)d_in[17];
    const float* obias = (const float*)d_in[18];
    const float* w1    = (const float*)d_in[19];
    const float* b1    = (const float*)d_in[20];
    const float* w2    = (const float*)d_in[21];
    const float* b2    = (const float*)d_in[22];
    const float* w3    = (const float*)d_in[23];
    const float* b3    = (const float*)d_in[24];
    float* out = (float*)d_out;

    const long MB = 1048576;
    char* W = (char*)d_ws;
    float* x     = (float*)(W);            // [0,8M) residual fp32
    bf16*  attnb = (bf16*)(W + 8*MB);      // [8M,12M)
    bf16*  hb    = (bf16*)(W + 16*MB);     // [16M,32M) FFN hidden bf16
    bf16*  qb    = (bf16*)(W + 32*MB);     // [32M,36M)
    bf16*  kb    = (bf16*)(W + 36*MB);     // [36M,40M)
    bf16*  vt    = (bf16*)(W + 44*MB);     // [44M,48M) V tile-blocked [bh][kt][d][k]
    bf16*  xnb   = (bf16*)(W + 48*MB);     // [48M,52M) LN out bf16
    bf16*  wt    = (bf16*)(W + 52*MB);     // [52M,55M) weights bf16 K-major
    float* bits  = (float*)(W + 55*MB);    // 2 KB
    bf16*  oqb   = (bf16*)(W + 56*MB);     // 64 KB
    float* cosT  = (float*)(W + 57*MB);    // 256 KB
    float* sinT  = cosT + 65536;           // 256 KB
    float* w2t   = (float*)(W + 58*MB);    // 16 KB
    bf16*  xfb   = (bf16*)(W + 32*MB);     // final LN bf16 (aliases dead qb)
    float* g     = (float*)(W + 36*MB);    // 32 KB (aliases dead kb)
    float* S     = (float*)(W + 40*MB);    // [40M,44M) scores fp32
    // wt per-layer offsets (bf16 elems), layer stride 786432:
    //   qkvT +0 | projT +196608 | f1T +262144 | f2T +524288

    k_wtall<<<dim3(32, 32, 9), dim3(32,8), 0, stream>>>(qkvw, projw, f1w, f2w, wt,
                                                        oq, oqb, cosT, sinT, w2, w2t);

    k_embln<<<NROW/4, 256, 0, stream>>>(tok, emb, ln1w, ln1b, x, xnb);
    for (int l=0; l<2; l++){
        long L = (long)l*786432;
        if (l) k_lnb<<<NROW/4, 256, 0, stream>>>(x, ln1w + l*DD, ln1b + l*DD, xnb);
        k_mgemmQKV<<<dim3(768/64, 64), 256, 0, stream>>>(
            xnb, wt + L, qkvb + l*768, cosT, sinT, qb, kb, vt);
        k_fattn<<<dim3(TT/64, BB*HH), 256, 0, stream>>>(qb, kb, vt, attnb);
        k_mgemm64<<<dim3(256/64, NROW/64), 256, 0, stream>>>(
            attnb, wt + L + 196608, projb + l*DD, x, (bf16*)0, 256, 256, 1);
        k_lnb<<<NROW/4, 256, 0, stream>>>(x, ln2w + l*DD, ln2b + l*DD, xnb);
        k_mgemm<<<dim3(1024/64, 64), 256, 0, stream>>>(
            xnb, wt + L + 262144, f1b + l*1024, (float*)0, hb, 256, 1024, 2);
        k_mgemm64<<<dim3(256/64, NROW/64), 256, 0, stream>>>(
            hb, wt + L + 524288, f2bb + l*DD, x, (bf16*)0, 1024, 256, 1);
    }
    k_lnf<<<NROW/4, 256, 0, stream>>>(x, lnfw, lnfb, ow, xfb, g);
    // outputs: sum_all [0,260) | pairs [260,772) | q_attn [772, 772+4*128*2048)
    k_score<<<dim3(TT/32, BB), 256, 0, stream>>>(oqb, xfb, S);
    k_psoft<<<BB*NQ, 256, 0, stream>>>(S, g, obias, out + 772, out + 260, bits);
    k_scan<<<4, 64, 0, stream>>>(bits, w1, b1, w2t, b2, w3, b3, out);
}

// Round 17
// 353.786 us; speedup vs baseline: 1.0310x; 1.0079x over previous
//
#include <hip/hip_runtime.h>
#include <hip/hip_bf16.h>

#define BB 4
#define TT 2048
#define DD 256
#define HH 4
#define HDD 64
#define NROW 8192   // B*T
#define NQ 128      // MAX_BITS*2

typedef __hip_bfloat16 bf16;
typedef __attribute__((ext_vector_type(8))) short bf8v;   // 8 bf16 = 4 VGPR
typedef __attribute__((ext_vector_type(4))) short bf4v;   // 4 bf16 = 2 VGPR
typedef __attribute__((ext_vector_type(4))) float f4v;
typedef __attribute__((ext_vector_type(2))) unsigned int u2v;

__device__ __forceinline__ bf16 f2b(float v){ return __float2bfloat16(v); }
__device__ __forceinline__ short f2bs(float v){
    bf16 h = __float2bfloat16(v);
    return *reinterpret_cast<short*>(&h);
}
__device__ __forceinline__ float bs2f(short s){
    bf16 h = *reinterpret_cast<bf16*>(&s);
    return __bfloat162float(h);
}
__device__ __forceinline__ float rl(float v, int l){
    return __uint_as_float(__builtin_amdgcn_readlane(__float_as_uint(v), l));
}

// DPP rotate ops within 16-lane row (all lanes valid, full masks)
#define DPP_ROR_ADD(v, ctrl) \
    ((v) + __int_as_float(__builtin_amdgcn_update_dpp(0, __float_as_int(v), (ctrl), 0xF, 0xF, false)))
#define DPP_ROR_MAX(v, ctrl) \
    fmaxf((v), __int_as_float(__builtin_amdgcn_update_dpp(0, __float_as_int(v), (ctrl), 0xF, 0xF, false)))

// gfx950 permlane swap via builtin (R4 fix: asm "+v"(a),"+v"(b) with a==b let
// regalloc coalesce both into ONE VGPR -> in-place garbage shuffle).
__device__ __forceinline__ void plswap16(float v, float& a, float& b){
#if __has_builtin(__builtin_amdgcn_permlane16_swap)
    u2v r = __builtin_amdgcn_permlane16_swap(__float_as_uint(v), __float_as_uint(v), false, false);
    a = __uint_as_float(r.x); b = __uint_as_float(r.y);
#else
    a = v; b = v;
    asm volatile("" : "+v"(b));
    asm("v_permlane16_swap_b32 %0, %1" : "+v"(a), "+v"(b));
#endif
}
__device__ __forceinline__ void plswap32(float v, float& a, float& b){
#if __has_builtin(__builtin_amdgcn_permlane32_swap)
    u2v r = __builtin_amdgcn_permlane32_swap(__float_as_uint(v), __float_as_uint(v), false, false);
    a = __uint_as_float(r.x); b = __uint_as_float(r.y);
#else
    a = v; b = v;
    asm volatile("" : "+v"(b));
    asm("v_permlane32_swap_b32 %0, %1" : "+v"(a), "+v"(b));
#endif
}
__device__ __forceinline__ float swap16_add(float v){ float a,b; plswap16(v,a,b); return a + b; }
__device__ __forceinline__ float swap32_add(float v){ float a,b; plswap32(v,a,b); return a + b; }
__device__ __forceinline__ float swap16_max(float v){ float a,b; plswap16(v,a,b); return fmaxf(a,b); }
__device__ __forceinline__ float swap32_max(float v){ float a,b; plswap32(v,a,b); return fmaxf(a,b); }
__device__ __forceinline__ float wsum(float v){
    v = DPP_ROR_ADD(v, 0x121); v = DPP_ROR_ADD(v, 0x122);
    v = DPP_ROR_ADD(v, 0x124); v = DPP_ROR_ADD(v, 0x128);
    v = swap16_add(v); v = swap32_add(v);
    return v;
}
__device__ __forceinline__ float wmax(float v){
    v = DPP_ROR_MAX(v, 0x121); v = DPP_ROR_MAX(v, 0x122);
    v = DPP_ROR_MAX(v, 0x124); v = DPP_ROR_MAX(v, 0x128);
    v = swap16_max(v); v = swap32_max(v);
    return v;
}

#define MFMA32(A,B,C) __builtin_amdgcn_mfma_f32_16x16x32_bf16((A),(B),(C),0,0,0)
#if __has_builtin(__builtin_amdgcn_mfma_f32_16x16x16bf16_1k)
#define MFMA16(A,B,C) __builtin_amdgcn_mfma_f32_16x16x16bf16_1k((A),(B),(C),0,0,0)
#else
__device__ __forceinline__ f4v mfma16_asm(bf4v a, bf4v b, f4v c){
    f4v d;
    asm("v_mfma_f32_16x16x16_bf16 %0, %1, %2, %3" : "=v"(d) : "v"(a), "v"(b), "v"(c));
    return d;
}
#define MFMA16(A,B,C) mfma16_asm((A),(B),(C))
#endif

// ---------------- prologue mega-kernel ----------------
// z 0..7: 8 weight cast+transposes | z==8: trig tables + oq cast + w2t
// z 9..10: fused embed + layer-0 LN1 (R17: folded from separate dispatch;
// independent work, runs concurrently with weight slices, one fewer launch)
__global__ __launch_bounds__(256) void k_wtall(const float* __restrict__ qkvw,
                                               const float* __restrict__ projw,
                                               const float* __restrict__ f1w,
                                               const float* __restrict__ f2w,
                                               bf16* __restrict__ wt,
                                               const float* __restrict__ oq, bf16* __restrict__ oqb,
                                               float* __restrict__ cosT, float* __restrict__ sinT,
                                               const float* __restrict__ w2, float* __restrict__ w2t,
                                               const int* __restrict__ tok,
                                               const float* __restrict__ emb,
                                               const float* __restrict__ ln1w,
                                               const float* __restrict__ ln1b,
                                               float* __restrict__ x,
                                               bf16* __restrict__ xnb){
    __shared__ float t[32][33];
    int z = blockIdx.z;
    if (z >= 9){
        // embed + LN1(layer 0): 2 slices x 1024 blocks x 4 rows (64 lanes/row).
        // tid linearization (x fastest) == HW lane order, so wave-wide DPP/
        // permlane reductions see lane = tid&63 exactly as in the old kernel.
        int bid = blockIdx.y*32 + blockIdx.x;             // 0..1023
        int tid = threadIdx.y*32 + threadIdx.x;           // 0..255
        int row = (z-9)*4096 + bid*4 + (tid >> 6);        // 0..8191
        int lane = tid & 63;
        f4v v = *(const f4v*)(emb + (long)tok[row]*DD + lane*4);
        *(f4v*)(x + (long)row*DD + lane*4) = v;
        float s  = (v[0]+v[1]) + (v[2]+v[3]);
        float s2 = (v[0]*v[0]+v[1]*v[1]) + (v[2]*v[2]+v[3]*v[3]);
        s = wsum(s); s2 = wsum(s2);
        float mu  = s * (1.0f/DD);
        float var = s2 * (1.0f/DD) - mu*mu;
        float rs  = rsqrtf(var + 1e-5f);
        f4v wv4 = *(const f4v*)(ln1w + lane*4);
        f4v bv4 = *(const f4v*)(ln1b + lane*4);
        bf4v o;
        #pragma unroll
        for (int i=0;i<4;i++) o[i] = f2bs((v[i]-mu)*rs*wv4[i] + bv4[i]);
        *(bf4v*)(xnb + (long)row*DD + lane*4) = o;
        return;
    }
    if (z == 8){
        int bid = blockIdx.y*32 + blockIdx.x;
        if (bid >= 256) return;
        int gid = bid*256 + threadIdx.y*32 + threadIdx.x;   // 0..65535
        int tt = gid >> 5, dd = gid & 31;
        float invf = powf(10000.0f, -(float)(2*dd)/64.0f);
        float ang = (float)tt * invf;
        float sn, cs;
        sincosf(ang, &sn, &cs);
        cosT[gid] = cs; sinT[gid] = sn;
        if (gid < NQ*DD) oqb[gid] = f2b(oq[gid]);
        if (gid < 4096){ int j = gid >> 6, k = gid & 63; w2t[gid] = w2[k*64 + j]; }
        return;
    }
    int l = z >> 2, type = z & 3;
    long L = (long)l*786432;
    int K, M; const float* src; long doff;
    if (type == 0){ K=256;  M=768;  src = qkvw + (long)l*256*768;  doff = L; }
    else if (type == 1){ K=256;  M=256;  src = projw + (long)l*256*256; doff = L + 196608; }
    else if (type == 2){ K=256;  M=1024; src = f1w  + (long)l*256*1024; doff = L + 262144; }
    else               { K=1024; M=256;  src = f2w  + (long)l*1024*256; doff = L + 524288; }
    int m0 = blockIdx.x*32, k0 = blockIdx.y*32;
    if (m0 >= M || k0 >= K) return;
    bf16* dst = wt + doff;
    int tx = threadIdx.x, ty = threadIdx.y;     // 32 x 8
    #pragma unroll
    for (int i=0;i<4;i++)
        t[ty+i*8][tx] = src[(long)(k0+ty+i*8)*M + m0 + tx];
    __syncthreads();
    #pragma unroll
    for (int i=0;i<4;i++)
        dst[(long)(m0+ty+i*8)*K + k0 + tx] = f2b(t[tx][ty+i*8]);
}

// ---------------- layernorm, bf16 out (1 wave = 1 row, barrier-free) ----------------
__global__ __launch_bounds__(256) void k_lnb(const float* __restrict__ X,
                                             const float* __restrict__ w,
                                             const float* __restrict__ b,
                                             bf16* __restrict__ Y){
    int row = blockIdx.x*4 + (threadIdx.x >> 6);
    int lane = threadIdx.x & 63;
    f4v v = *(const f4v*)(X + (long)row*DD + lane*4);
    float s  = (v[0]+v[1]) + (v[2]+v[3]);
    float s2 = (v[0]*v[0]+v[1]*v[1]) + (v[2]*v[2]+v[3]*v[3]);
    s = wsum(s); s2 = wsum(s2);
    float mu  = s * (1.0f/DD);
    float var = s2 * (1.0f/DD) - mu*mu;
    float rs  = rsqrtf(var + 1e-5f);
    f4v wv4 = *(const f4v*)(w + lane*4);
    f4v bv4 = *(const f4v*)(b + lane*4);
    bf4v o;
    #pragma unroll
    for (int i=0;i<4;i++) o[i] = f2bs((v[i]-mu)*rs*wv4[i] + bv4[i]);
    *(bf4v*)(Y + (long)row*DD + lane*4) = o;
}

// ---------------- final layernorm: bf16 out + g[n] = y . ow ----------------
__global__ __launch_bounds__(256) void k_lnf(const float* __restrict__ X,
                                             const float* __restrict__ w,
                                             const float* __restrict__ b,
                                             const float* __restrict__ ow,
                                             bf16* __restrict__ Yb,
                                             float* __restrict__ g){
    int row = blockIdx.x*4 + (threadIdx.x >> 6);
    int lane = threadIdx.x & 63;
    f4v v = *(const f4v*)(X + (long)row*DD + lane*4);
    float s  = (v[0]+v[1]) + (v[2]+v[3]);
    float s2 = (v[0]*v[0]+v[1]*v[1]) + (v[2]*v[2]+v[3]*v[3]);
    s = wsum(s); s2 = wsum(s2);
    float mu  = s * (1.0f/DD);
    float var = s2 * (1.0f/DD) - mu*mu;
    float rs  = rsqrtf(var + 1e-5f);
    f4v wv4 = *(const f4v*)(w + lane*4);
    f4v bv4 = *(const f4v*)(b + lane*4);
    f4v ov4 = *(const f4v*)(ow + lane*4);
    bf4v o;
    float gp = 0.f;
    #pragma unroll
    for (int i=0;i<4;i++){
        float y = (v[i]-mu)*rs*wv4[i] + bv4[i];
        o[i] = f2bs(y);
        gp += y * ov4[i];
    }
    *(bf4v*)(Yb + (long)row*DD + lane*4) = o;
    gp = wsum(gp);
    if (lane == 0) g[row] = gp;
}

// ---------------- MFMA GEMM 128x64 tile (ffn1): R11 dbuf (verified best) ----------------
__global__ __launch_bounds__(256) void k_mgemm(const bf16* __restrict__ A,
                                               const bf16* __restrict__ Wt,
                                               const float* __restrict__ bias,
                                               float* __restrict__ Cf,
                                               bf16* __restrict__ Cb,
                                               int K, int M, int mode){
    __shared__ short As[2][128*64];
    __shared__ short Ws[2][64*64];
    int tid = threadIdx.x;
    int lane = tid & 63, wv = tid >> 6;
    int n0 = blockIdx.y * 128, m0 = blockIdx.x * 64;
    int rbase = (wv >> 1) * 64, cbase = (wv & 1) * 32;
    f4v acc[4][2] = {};
    bf8v va[4], vw[2];
    #pragma unroll
    for (int c=0;c<4;c++){
        int idx = c*256 + tid;                 // row = idx>>3 (0..127)
        va[c] = *(const bf8v*)(A + (long)(n0 + (idx>>3))*K + ((idx&7)<<3));
    }
    #pragma unroll
    for (int c=0;c<2;c++){
        int idx = c*256 + tid;                 // row 0..63
        vw[c] = *(const bf8v*)(Wt + (long)(m0 + (idx>>3))*K + ((idx&7)<<3));
    }
    int buf = 0;
    for (int k0 = 0; k0 < K; k0 += 64){
        #pragma unroll
        for (int c=0;c<4;c++){
            int idx = c*256 + tid, row = idx>>3;
            *(bf8v*)&As[buf][row*64 + (((idx&7)<<3) ^ ((row&7)<<3))] = va[c];
        }
        #pragma unroll
        for (int c=0;c<2;c++){
            int idx = c*256 + tid, row = idx>>3;
            *(bf8v*)&Ws[buf][row*64 + (((idx&7)<<3) ^ ((row&7)<<3))] = vw[c];
        }
        __syncthreads();    // buf ready; also fences i+2's rewrite
        if (k0 + 64 < K){   // next-tile loads overlap compute
            #pragma unroll
            for (int c=0;c<4;c++){
                int idx = c*256 + tid;
                va[c] = *(const bf8v*)(A + (long)(n0 + (idx>>3))*K + k0 + 64 + ((idx&7)<<3));
            }
            #pragma unroll
            for (int c=0;c<2;c++){
                int idx = c*256 + tid;
                vw[c] = *(const bf8v*)(Wt + (long)(m0 + (idx>>3))*K + k0 + 64 + ((idx&7)<<3));
            }
        }
        int k8 = (lane >> 4) << 3;
        #pragma unroll
        for (int h=0; h<2; h++){
            bf8v af[4], bfr[2];
            #pragma unroll
            for (int i=0;i<4;i++){
                int row = rbase + i*16 + (lane&15);
                af[i] = *(bf8v*)&As[buf][row*64 + ((h*32 + k8) ^ ((row&7)<<3))];
            }
            #pragma unroll
            for (int j=0;j<2;j++){
                int row = cbase + j*16 + (lane&15);
                bfr[j] = *(bf8v*)&Ws[buf][row*64 + ((h*32 + k8) ^ ((row&7)<<3))];
            }
            #pragma unroll
            for (int i=0;i<4;i++)
                #pragma unroll
                for (int j=0;j<2;j++)
                    acc[i][j] = MFMA32(af[i], bfr[j], acc[i][j]);
        }
        buf ^= 1;
    }
    int rq = (lane >> 4) * 4;
    int cl = lane & 15;
    #pragma unroll
    for (int i=0;i<4;i++){
        #pragma unroll
        for (int j=0;j<2;j++){
            int m = m0 + cbase + j*16 + cl;
            float bs = bias[m];
            #pragma unroll
            for (int r=0;r<4;r++){
                int n = n0 + rbase + i*16 + rq + r;
                float v = acc[i][j][r] + bs;
                long idx = (long)n*M + m;
                if (mode == 0)      Cf[idx] = v;
                else if (mode == 1) Cf[idx] += v;
                else if (mode == 2) Cb[idx] = f2b(0.5f*v*(1.0f + erff(v*0.70710678118654752f)));
                else                Cb[idx] = f2b(v);
            }
        }
    }
}

// ---------------- MFMA GEMM 64x64 tile (proj/ffn2: M=256, 2 blocks/CU) ----------------
__global__ __launch_bounds__(256) void k_mgemm64(const bf16* __restrict__ A,
                                                 const bf16* __restrict__ Wt,
                                                 const float* __restrict__ bias,
                                                 float* __restrict__ Cf,
                                                 bf16* __restrict__ Cb,
                                                 int K, int M, int mode){
    __shared__ short As[2][64*64];
    __shared__ short Ws[2][64*64];
    int tid = threadIdx.x;
    int lane = tid & 63, wv = tid >> 6;
    int n0 = blockIdx.y * 64, m0 = blockIdx.x * 64;
    int rbase = (wv >> 1) * 32, cbase = (wv & 1) * 32;
    f4v acc[2][2] = {};
    bf8v va[2], vw[2];
    #pragma unroll
    for (int c=0;c<2;c++){
        int idx = c*256 + tid;                 // row = idx>>3 (0..63)
        va[c] = *(const bf8v*)(A  + (long)(n0 + (idx>>3))*K + ((idx&7)<<3));
        vw[c] = *(const bf8v*)(Wt + (long)(m0 + (idx>>3))*K + ((idx&7)<<3));
    }
    int buf = 0;
    for (int k0 = 0; k0 < K; k0 += 64){
        #pragma unroll
        for (int c=0;c<2;c++){
            int idx = c*256 + tid, row = idx>>3;
            *(bf8v*)&As[buf][row*64 + (((idx&7)<<3) ^ ((row&7)<<3))] = va[c];
            *(bf8v*)&Ws[buf][row*64 + (((idx&7)<<3) ^ ((row&7)<<3))] = vw[c];
        }
        __syncthreads();
        if (k0 + 64 < K){
            #pragma unroll
            for (int c=0;c<2;c++){
                int idx = c*256 + tid;
                va[c] = *(const bf8v*)(A  + (long)(n0 + (idx>>3))*K + k0 + 64 + ((idx&7)<<3));
                vw[c] = *(const bf8v*)(Wt + (long)(m0 + (idx>>3))*K + k0 + 64 + ((idx&7)<<3));
            }
        }
        int k8 = (lane >> 4) << 3;
        #pragma unroll
        for (int h=0; h<2; h++){
            bf8v af[2], bfr[2];
            #pragma unroll
            for (int i=0;i<2;i++){
                int row = rbase + i*16 + (lane&15);
                af[i] = *(bf8v*)&As[buf][row*64 + ((h*32 + k8) ^ ((row&7)<<3))];
            }
            #pragma unroll
            for (int j=0;j<2;j++){
                int row = cbase + j*16 + (lane&15);
                bfr[j] = *(bf8v*)&Ws[buf][row*64 + ((h*32 + k8) ^ ((row&7)<<3))];
            }
            #pragma unroll
            for (int i=0;i<2;i++)
                #pragma unroll
                for (int j=0;j<2;j++)
                    acc[i][j] = MFMA32(af[i], bfr[j], acc[i][j]);
        }
        buf ^= 1;
    }
    int rq = (lane >> 4) * 4;
    int cl = lane & 15;
    #pragma unroll
    for (int i=0;i<2;i++){
        #pragma unroll
        for (int j=0;j<2;j++){
            int m = m0 + cbase + j*16 + cl;
            float bs = bias[m];
            #pragma unroll
            for (int r=0;r<4;r++){
                int n = n0 + rbase + i*16 + rq + r;
                float v = acc[i][j][r] + bs;
                long idx = (long)n*M + m;
                if (mode == 0)      Cf[idx] = v;
                else if (mode == 1) Cf[idx] += v;
                else if (mode == 2) Cb[idx] = f2b(0.5f*v*(1.0f + erff(v*0.70710678118654752f)));
                else                Cb[idx] = f2b(v);
            }
        }
    }
}

// ---------------- fused QKV GEMM + bias + RoPE + V tile-transpose (R10-verified) ----------------
__global__ __launch_bounds__(256) void k_mgemmQKV(const bf16* __restrict__ A,
                                                  const bf16* __restrict__ Wt,
                                                  const float* __restrict__ bias,
                                                  const float* __restrict__ cosT,
                                                  const float* __restrict__ sinT,
                                                  bf16* __restrict__ qb,
                                                  bf16* __restrict__ kb,
                                                  bf16* __restrict__ vt){
    __shared__ short As[128*64];
    __shared__ short Ws[64*64];
    __shared__ short E[128][68];
    const int K = 256, M = 768;
    int tid = threadIdx.x;
    int lane = tid & 63, wv = tid >> 6;
    int n0 = blockIdx.y * 128, m0 = blockIdx.x * 64;
    int rbase = (wv >> 1) * 64, cbase = (wv & 1) * 32;
    f4v acc[4][2] = {};
    for (int k0 = 0; k0 < K; k0 += 64){
        bf8v va[4], vw[2];
        #pragma unroll
        for (int c=0;c<4;c++){
            int idx = c*256 + tid;
            va[c] = *(const bf8v*)(A + (long)(n0 + (idx>>3))*K + k0 + ((idx&7)<<3));
        }
        #pragma unroll
        for (int c=0;c<2;c++){
            int idx = c*256 + tid;
            vw[c] = *(const bf8v*)(Wt + (long)(m0 + (idx>>3))*K + k0 + ((idx&7)<<3));
        }
        __syncthreads();
        #pragma unroll
        for (int c=0;c<4;c++){
            int idx = c*256 + tid, row = idx>>3;
            *(bf8v*)&As[row*64 + (((idx&7)<<3) ^ ((row&7)<<3))] = va[c];
        }
        #pragma unroll
        for (int c=0;c<2;c++){
            int idx = c*256 + tid, row = idx>>3;
            *(bf8v*)&Ws[row*64 + (((idx&7)<<3) ^ ((row&7)<<3))] = vw[c];
        }
        __syncthreads();
        int k8 = (lane >> 4) << 3;
        #pragma unroll
        for (int h=0; h<2; h++){
            bf8v af[4], bfr[2];
            #pragma unroll
            for (int i=0;i<4;i++){
                int row = rbase + i*16 + (lane&15);
                af[i] = *(bf8v*)&As[row*64 + ((h*32 + k8) ^ ((row&7)<<3))];
            }
            #pragma unroll
            for (int j=0;j<2;j++){
                int row = cbase + j*16 + (lane&15);
                bfr[j] = *(bf8v*)&Ws[row*64 + ((h*32 + k8) ^ ((row&7)<<3))];
            }
            #pragma unroll
            for (int i=0;i<4;i++)
                #pragma unroll
                for (int j=0;j<2;j++)
                    acc[i][j] = MFMA32(af[i], bfr[j], acc[i][j]);
        }
    }
    int rq = (lane >> 4) * 4;
    int cl = lane & 15;
    #pragma unroll
    for (int i=0;i<4;i++){
        #pragma unroll
        for (int j=0;j<2;j++){
            int cc = cbase + j*16 + cl;
            float bs = bias[m0 + cc];
            #pragma unroll
            for (int r=0;r<4;r++)
                E[rbase + i*16 + rq + r][cc] = f2bs(acc[i][j][r] + bs);
        }
    }
    __syncthreads();
    int part = m0 >> 8;
    int h = (m0 >> 6) & 3;
    int b = n0 >> 11;
    int t0 = n0 & 2047;
    int bh = b*HH + h;
    if (part < 2){
        bf16* dst0 = part ? kb : qb;
        int r2 = tid >> 2;
        int c0 = (tid & 3) * 16;
        int cpx = c0 ^ 32;
        #pragma unroll
        for (int half=0; half<2; half++){
            int row = half*64 + r2;
            int t = t0 + row;
            bf8v e0 = *(bf8v*)&E[row][c0];
            bf8v e1 = *(bf8v*)&E[row][c0+8];
            bf8v p0 = *(bf8v*)&E[row][cpx];
            bf8v p1 = *(bf8v*)&E[row][cpx+8];
            const float* ct = cosT + t*32;
            const float* st = sinT + t*32;
            short o[16];
            #pragma unroll
            for (int i=0;i<8;i++){
                int d = c0 + i, dd = d & 31;
                float cs = ct[dd], sn = st[dd];
                float v = bs2f(e0[i]), v2 = bs2f(p0[i]);
                o[i] = f2bs((d < 32) ? (v*cs - v2*sn) : (v*cs + v2*sn));
            }
            #pragma unroll
            for (int i=0;i<8;i++){
                int d = c0 + 8 + i, dd = d & 31;
                float cs = ct[dd], sn = st[dd];
                float v = bs2f(e1[i]), v2 = bs2f(p1[i]);
                o[8+i] = f2bs((d < 32) ? (v*cs - v2*sn) : (v*cs + v2*sn));
            }
            short* dp = (short*)dst0 + ((long)bh*TT + t)*64 + c0;
            *(bf8v*)dp     = *(bf8v*)&o[0];
            *(bf8v*)(dp+8) = *(bf8v*)&o[8];
        }
    } else {
        int tIdx0 = t0 >> 6;
        int d  = (tid & 127) >> 1;
        int k0 = (tid & 1) * 32;
        int tt = tid >> 7;
        short o[32];
        #pragma unroll
        for (int k=0;k<32;k++) o[k] = E[tt*64 + k0 + k][d];
        short* dp = (short*)vt + (((long)bh*32 + tIdx0 + tt)*64 + d)*64 + k0;
        *(bf8v*)dp      = *(bf8v*)&o[0];
        *(bf8v*)(dp+8)  = *(bf8v*)&o[8];
        *(bf8v*)(dp+16) = *(bf8v*)&o[16];
        *(bf8v*)(dp+24) = *(bf8v*)&o[24];
    }
}

// ---------------- MFMA flash causal attention (R4-exact, thrice-verified ~42us; PARKED) ----------------
__global__ __launch_bounds__(256) void k_fattn(const bf16* __restrict__ qb,
                                               const bf16* __restrict__ kb,
                                               const bf16* __restrict__ vt,
                                               bf16* __restrict__ ob){
    __shared__ short Ks[2][64][72];
    __shared__ short Vs[2][64][68];
    int bh = blockIdx.y;
    int qt = (int)(gridDim.x - 1) - (int)blockIdx.x;  // heavy tiles first
    int tid = threadIdx.x;
    int lane = tid & 63, w = tid >> 6;
    int col = lane & 15, quad = lane >> 4;
    int q0 = qt*64 + w*16;
    const bf16* qp = qb + ((long)bh*TT + q0 + col)*64 + quad*8;
    bf8v bq0 = *(const bf8v*)(qp);
    bf8v bq1 = *(const bf8v*)(qp + 32);
    f4v oc[4] = {};
    float lsum = 0.f;
    int qglob = q0 + col;
    int srow = tid >> 2, sc0 = (tid & 3) * 16;
    const short* kgb = (const short*)kb + ((long)bh*TT + srow)*64 + sc0;
    const short* vgb = (const short*)vt + (((long)bh*32)*64 + srow)*64 + sc0;

    bf8v pk0 = *(const bf8v*)kgb;
    bf8v pk1 = *(const bf8v*)(kgb + 8);
    bf8v pv0 = *(const bf8v*)vgb;
    bf8v pv1 = *(const bf8v*)(vgb + 8);
    *(bf8v*)&Ks[0][srow][sc0]     = pk0;
    *(bf8v*)&Ks[0][srow][sc0 + 8] = pk1;
    *(bf8v*)&Vs[0][srow][sc0]     = pv0;
    *(bf8v*)&Vs[0][srow][sc0 + 8] = pv1;

    int buf = 0;
    for (int kt=0; kt<=qt; kt++){
        __syncthreads();
        bool more = (kt < qt);
        if (more){
            const short* kg = kgb + (long)(kt+1)*4096;
            const short* vg = vgb + (long)(kt+1)*4096;
            pk0 = *(const bf8v*)kg;
            pk1 = *(const bf8v*)(kg + 8);
            pv0 = *(const bf8v*)vg;
            pv1 = *(const bf8v*)(vg + 8);
        }
        bool diag = (kt == qt);
        int ntmax = diag ? w : 3;
        bf4v bp[4];
        #pragma unroll
        for (int nt=0; nt<4; nt++){
            if (nt > ntmax) continue;
            bf8v ka0 = *(const bf8v*)&Ks[buf][nt*16 + col][quad*8];
            bf8v ka1 = *(const bf8v*)&Ks[buf][nt*16 + col][32 + quad*8];
            f4v st = {};
            st = MFMA32(ka0, bq0, st);
            st = MFMA32(ka1, bq1, st);
            int key0 = kt*64 + nt*16 + quad*4;
            bf4v pb;
            #pragma unroll
            for (int r=0; r<4; r++){
                float e = __expf(st[r]*0.125f);
                if (diag && (key0 + r > qglob)) e = 0.f;
                lsum += e;
                pb[r] = f2bs(e);
            }
            bp[nt] = pb;
        }
        #pragma unroll
        for (int dt=0; dt<4; dt++){
            #pragma unroll
            for (int nt=0; nt<4; nt++){
                if (nt > ntmax) continue;
                bf4v va = *(const bf4v*)&Vs[buf][dt*16 + col][nt*16 + quad*4];
                oc[dt] = MFMA16(va, bp[nt], oc[dt]);
            }
        }
        if (more){
            *(bf8v*)&Ks[buf^1][srow][sc0]     = pk0;
            *(bf8v*)&Ks[buf^1][srow][sc0 + 8] = pk1;
            *(bf8v*)&Vs[buf^1][srow][sc0]     = pv0;
            *(bf8v*)&Vs[buf^1][srow][sc0 + 8] = pv1;
        }
        buf ^= 1;
    }
    lsum += __shfl_xor(lsum, 16, 64);
    lsum += __shfl_xor(lsum, 32, 64);
    float linv = 1.0f / lsum;

    int b = bh / HH, h = bh % HH;
    long obase = ((long)b*TT + q0 + col)*DD + h*64 + quad*4;
    #pragma unroll
    for (int dt=0; dt<4; dt++){
        bf4v o4;
        #pragma unroll
        for (int r=0; r<4; r++) o4[r] = f2bs(oc[dt][r]*linv);
        *(bf4v*)(ob + obase + dt*16) = o4;
    }
}

// ---------------- pooling scores: S[b][q][t] = (oq[q] . xf[b,t]) / 16, MFMA ----------------
__global__ __launch_bounds__(256) void k_score(const bf16* __restrict__ oqb,
                                               const bf16* __restrict__ xfb,
                                               float* __restrict__ S){
    int b = blockIdx.y, t0 = blockIdx.x*32;
    int tid = threadIdx.x, lane = tid & 63, w = tid >> 6;
    int col = lane & 15, quad = lane >> 4, k8 = quad << 3;
    const bf16* xb = xfb + (long)b*TT*DD;
    f4v acc[2][2] = {};
    #pragma unroll
    for (int ko=0; ko<8; ko++){
        int kk = ko*32 + k8;
        bf8v a0 = *(const bf8v*)(oqb + (long)(w*32 +      col)*DD + kk);
        bf8v a1 = *(const bf8v*)(oqb + (long)(w*32 + 16 + col)*DD + kk);
        #pragma unroll
        for (int bt=0; bt<2; bt++){
            bf8v bv = *(const bf8v*)(xb + (long)(t0 + bt*16 + col)*DD + kk);
            acc[0][bt] = MFMA32(a0, bv, acc[0][bt]);
            acc[1][bt] = MFMA32(a1, bv, acc[1][bt]);
        }
    }
    #pragma unroll
    for (int qt2=0; qt2<2; qt2++){
        #pragma unroll
        for (int bt=0; bt<2; bt++){
            #pragma unroll
            for (int r=0; r<4; r++){
                int q = w*32 + qt2*16 + quad*4 + r;
                S[((long)b*NQ + q)*TT + t0 + bt*16 + col] = acc[qt2][bt][r]*0.0625f;
            }
        }
    }
}

// ---------------- softmax row + fused bit: one (b,q) per block ----------------
__global__ __launch_bounds__(256) void k_psoft(const float* __restrict__ S,
                                               const float* __restrict__ g,
                                               const float* __restrict__ obias,
                                               float* __restrict__ out_qattn,
                                               float* __restrict__ out_pairs,
                                               float* __restrict__ bits){
    __shared__ float cmax[4], cs[4], cg[4];
    int bq = blockIdx.x, b = bq >> 7;
    int tid = threadIdx.x, wv = tid >> 6, lane = tid & 63;
    const f4v* S4 = (const f4v*)(S + (long)bq*TT);
    f4v s0 = S4[tid], s1 = S4[tid + 256];
    float lmax = fmaxf(fmaxf(fmaxf(s0[0],s0[1]), fmaxf(s0[2],s0[3])),
                       fmaxf(fmaxf(s1[0],s1[1]), fmaxf(s1[2],s1[3])));
    lmax = wmax(lmax);
    if (lane == 0) cmax[wv] = lmax;
    __syncthreads();
    float m = fmaxf(fmaxf(cmax[0],cmax[1]), fmaxf(cmax[2],cmax[3]));
    const f4v* g4 = (const f4v*)(g + (long)b*TT);
    f4v gv0 = g4[tid], gv1 = g4[tid + 256];
    f4v e0, e1;
    #pragma unroll
    for (int i=0;i<4;i++){ e0[i] = __expf(s0[i]-m); e1[i] = __expf(s1[i]-m); }
    float lsum = (e0[0]+e0[1]+e0[2]+e0[3]) + (e1[0]+e1[1]+e1[2]+e1[3]);
    float gdot = (e0[0]*gv0[0]+e0[1]*gv0[1]+e0[2]*gv0[2]+e0[3]*gv0[3])
               + (e1[0]*gv1[0]+e1[1]*gv1[1]+e1[2]*gv1[2]+e1[3]*gv1[3]);
    lsum = wsum(lsum); gdot = wsum(gdot);
    if (lane == 0){ cs[wv] = lsum; cg[wv] = gdot; }
    __syncthreads();
    float Lr = (cs[0]+cs[1]) + (cs[2]+cs[3]);
    float G  = (cg[0]+cg[1]) + (cg[2]+cg[3]);
    float inv = 1.0f / Lr;
    f4v* out4 = (f4v*)(out_qattn + (long)bq*TT);
    out4[tid]       = e0 * inv;
    out4[tid + 256] = e1 * inv;
    if (tid == 0){
        float bit = 1.0f/(1.0f + expf(-(G*inv + obias[0])));
        bits[bq] = bit;
        out_pairs[bq] = bit;
    }
}

// ---------------- sequential 64-step carry MLP ----------------
__global__ __launch_bounds__(64) void k_scan(const float* __restrict__ bits,
                                             const float* __restrict__ w1, const float* __restrict__ b1,
                                             const float* __restrict__ w2t, const float* __restrict__ b2,
                                             const float* __restrict__ w3, const float* __restrict__ b3,
                                             float* __restrict__ out_sum){
    __shared__ __align__(16) float h1s[2][64];
    int b = blockIdx.x, lane = threadIdx.x;
    float w1c0 = w1[lane], w1c1 = w1[64 + lane], w1c2 = w1[128 + lane];
    float b1v = b1[lane], b2v = b2[lane];
    float w3c0 = w3[lane*2 + 0], w3c1 = w3[lane*2 + 1];
    float b30 = b3[0], b31 = b3[1];
    const f4v* wrow = (const f4v*)(w2t + (long)lane*64);
    f4v c0v = wrow[0],  c1v = wrow[1],  c2v = wrow[2],  c3v = wrow[3],
        c4v = wrow[4],  c5v = wrow[5],  c6v = wrow[6],  c7v = wrow[7],
        c8v = wrow[8],  c9v = wrow[9],  cav = wrow[10], cbv = wrow[11],
        ccv = wrow[12], cdv = wrow[13], cev = wrow[14], cfv = wrow[15];
    float z0v = bits[b*128 + lane*2 + 0];
    float z1v = bits[b*128 + lane*2 + 1];
    float carry = 0.f;
    float a1 = rl(z0v, 0)*w1c0 + rl(z1v, 0)*w1c1 + b1v;
    for (int step=0; step<64; step++){
        float h1 = fmaxf(carry*w1c2 + a1, 0.f);
        float* hb = h1s[step & 1];
        hb[lane] = h1;
        __syncthreads();
        if (step < 63){   // next step's carry-independent part, hidden under LDS
            a1 = rl(z0v, step+1)*w1c0 + rl(z1v, step+1)*w1c1 + b1v;
        }
        const f4v* hv = (const f4v*)hb;
        f4v va = hv[0]*c0v,  vb = hv[1]*c1v,  vc = hv[2]*c2v,   vd = hv[3]*c3v;
        va += hv[4]*c4v;   vb += hv[5]*c5v;   vc += hv[6]*c6v;   vd += hv[7]*c7v;
        va += hv[8]*c8v;   vb += hv[9]*c9v;   vc += hv[10]*cav;  vd += hv[11]*cbv;
        va += hv[12]*ccv;  vb += hv[13]*cdv;  vc += hv[14]*cev;  vd += hv[15]*cfv;
        f4v vs = (va + vb) + (vc + vd);
        float h2 = fmaxf(((vs[0] + vs[1]) + (vs[2] + vs[3])) + b2v, 0.f);
        float t0 = h2*w3c0, t1 = h2*w3c1;
        t0 = DPP_ROR_ADD(t0, 0x121); t1 = DPP_ROR_ADD(t1, 0x121);   // ror:1
        t0 = DPP_ROR_ADD(t0, 0x122); t1 = DPP_ROR_ADD(t1, 0x122);   // ror:2
        t0 = DPP_ROR_ADD(t0, 0x124); t1 = DPP_ROR_ADD(t1, 0x124);   // ror:4
        t0 = DPP_ROR_ADD(t0, 0x128); t1 = DPP_ROR_ADD(t1, 0x128);   // ror:8
        t0 = swap16_add(t0); t1 = swap16_add(t1);
        t0 = swap32_add(t0); t1 = swap32_add(t1);
        float o0 = 1.0f/(1.0f + __expf(-(t0 + b30)));
        carry    = 1.0f/(1.0f + __expf(-(t1 + b31)));
        if (lane == 0) out_sum[b*65 + step] = o0;
    }
    if (lane == 0) out_sum[b*65 + 64] = carry;
}

extern "C" void kernel_launch(void* const* d_in, const int* in_sizes, int n_in,
                              void* d_out, int out_size, void* d_ws, size_t ws_size,
                              hipStream_t stream){
    const int*   tok   = (const int*)d_in[0];
    const float* emb   = (const float*)d_in[1];
    const float* ln1w  = (const float*)d_in[2];
    const float* ln1b  = (const float*)d_in[3];
    const float* qkvw  = (const float*)d_in[4];
    const float* qkvb  = (const float*)d_in[5];
    const float* projw = (const float*)d_in[6];
    const float* projb = (const float*)d_in[7];
    const float* ln2w  = (const float*)d_in[8];
    const float* ln2b  = (const float*)d_in[9];
    const float* f1w   = (const float*)d_in[10];
    const float* f1b   = (const float*)d_in[11];
    const float* f2w   = (const float*)d_in[12];
    const float* f2bb  = (const float*)d_in[13];
    const float* lnfw  = (const float*)d_in[14];
    const float* lnfb  = (const float*)d_in[15];
    const float* oq    = (const float*)d_in[16];
    const float* ow    = (const float*)d_in[17];
    const float* obias = (const float*)d_in[18];
    const float* w1    = (const float*)d_in[19];
    const float* b1    = (const float*)d_in[20];
    const float* w2    = (const float*)d_in[21];
    const float* b2    = (const float*)d_in[22];
    const float* w3    = (const float*)d_in[23];
    const float* b3    = (const float*)d_in[24];
    float* out = (float*)d_out;

    const long MB = 1048576;
    char* W = (char*)d_ws;
    float* x     = (float*)(W);            // [0,8M) residual fp32
    bf16*  attnb = (bf16*)(W + 8*MB);      // [8M,12M)
    bf16*  hb    = (bf16*)(W + 16*MB);     // [16M,32M) FFN hidden bf16
    bf16*  qb    = (bf16*)(W + 32*MB);     // [32M,36M)
    bf16*  kb    = (bf16*)(W + 36*MB);     // [36M,40M)
    bf16*  vt    = (bf16*)(W + 44*MB);     // [44M,48M) V tile-blocked [bh][kt][d][k]
    bf16*  xnb   = (bf16*)(W + 48*MB);     // [48M,52M) LN out bf16
    bf16*  wt    = (bf16*)(W + 52*MB);     // [52M,55M) weights bf16 K-major
    float* bits  = (float*)(W + 55*MB);    // 2 KB
    bf16*  oqb   = (bf16*)(W + 56*MB);     // 64 KB
    float* cosT  = (float*)(W + 57*MB);    // 256 KB
    float* sinT  = cosT + 65536;           // 256 KB
    float* w2t   = (float*)(W + 58*MB);    // 16 KB
    bf16*  xfb   = (bf16*)(W + 32*MB);     // final LN bf16 (aliases dead qb)
    float* g     = (float*)(W + 36*MB);    // 32 KB (aliases dead kb)
    float* S     = (float*)(W + 40*MB);    // [40M,44M) scores fp32
    // wt per-layer offsets (bf16 elems), layer stride 786432:
    //   qkvT +0 | projT +196608 | f1T +262144 | f2T +524288

    // R17: prologue mega-kernel — weights (z0..7) + trig/misc (z8) + embed/LN1
    // (z9..10) in ONE dispatch (was two; independent work overlaps).
    k_wtall<<<dim3(32, 32, 11), dim3(32,8), 0, stream>>>(qkvw, projw, f1w, f2w, wt,
                                                         oq, oqb, cosT, sinT, w2, w2t,
                                                         tok, emb, ln1w, ln1b, x, xnb);

    for (int l=0; l<2; l++){
        long L = (long)l*786432;
        if (l) k_lnb<<<NROW/4, 256, 0, stream>>>(x, ln1w + l*DD, ln1b + l*DD, xnb);
        k_mgemmQKV<<<dim3(768/64, 64), 256, 0, stream>>>(
            xnb, wt + L, qkvb + l*768, cosT, sinT, qb, kb, vt);
        k_fattn<<<dim3(TT/64, BB*HH), 256, 0, stream>>>(qb, kb, vt, attnb);
        k_mgemm64<<<dim3(256/64, NROW/64), 256, 0, stream>>>(
            attnb, wt + L + 196608, projb + l*DD, x, (bf16*)0, 256, 256, 1);
        k_lnb<<<NROW/4, 256, 0, stream>>>(x, ln2w + l*DD, ln2b + l*DD, xnb);
        k_mgemm<<<dim3(1024/64, 64), 256, 0, stream>>>(
            xnb, wt + L + 262144, f1b + l*1024, (float*)0, hb, 256, 1024, 2);
        k_mgemm64<<<dim3(256/64, NROW/64), 256, 0, stream>>>(
            hb, wt + L + 524288, f2bb + l*DD, x, (bf16*)0, 1024, 256, 1);
    }
    k_lnf<<<NROW/4, 256, 0, stream>>>(x, lnfw, lnfb, ow, xfb, g);
    // outputs: sum_all [0,260) | pairs [260,772) | q_attn [772, 772+4*128*2048)
    k_score<<<dim3(TT/32, BB), 256, 0, stream>>>(oqb, xfb, S);
    k_psoft<<<BB*NQ, 256, 0, stream>>>(S, g, obias, out + 772, out + 260, bits);
    k_scan<<<4, 64, 0, stream>>>(bits, w1, b1, w2t, b2, w3, b3, out);
}